// Round 1
// baseline (1787.809 us; speedup 1.0000x reference)
//
#include <hip/hip_runtime.h>

#define B_ 128
#define T_ 20
#define V_ 10000
#define H_ 512
#define F_ 49
#define NBLK_ 128

typedef unsigned short u16;
typedef __attribute__((ext_vector_type(8))) short short8;
typedef __attribute__((ext_vector_type(4))) float floatx4;

#define GLOBAL_AS __attribute__((address_space(1)))
#define LDS_AS    __attribute__((address_space(3)))

__device__ inline void load_lds16(const void* g, void* l) {
    __builtin_amdgcn_global_load_lds((const GLOBAL_AS void*)g, (LDS_AS void*)l, 16, 0, 0);
}

// fp32 -> bf16 round-to-nearest-even
__device__ inline u16 f2b(float v) {
    unsigned u = __builtin_bit_cast(unsigned, v);
    unsigned rounding = 0x7FFFu + ((u >> 16) & 1u);
    return (u16)((u + rounding) >> 16);
}
__device__ inline float b2f(u16 h) {
    unsigned u = ((unsigned)h) << 16;
    return __builtin_bit_cast(float, u);
}
__device__ inline float fast_tanh(float x) {
    return 1.f - 2.f / (__expf(2.f * x) + 1.f);
}
__device__ inline float sigm(float x) { return 1.f / (1.f + __expf(-x)); }

// ---------------- transpose + convert: src[K,N] f32 -> dst[N,K] bf16 ----------------
__global__ __launch_bounds__(256) void transpose_cvt(const float* __restrict__ src,
                                                     u16* __restrict__ dst, int K, int N) {
    __shared__ float tile[32][33];
    int n0 = blockIdx.x * 32, k0 = blockIdx.y * 32;
    int tx = threadIdx.x, ty = threadIdx.y;   // 32 x 8
    #pragma unroll
    for (int i = 0; i < 32; i += 8) {
        int k = k0 + ty + i, n = n0 + tx;
        tile[ty + i][tx] = (k < K && n < N) ? src[(size_t)k * N + n] : 0.f;
    }
    __syncthreads();
    #pragma unroll
    for (int i = 0; i < 32; i += 8) {
        int n = n0 + ty + i, k = k0 + tx;
        if (n < N && k < K) dst[(size_t)n * K + k] = f2b(tile[tx][ty + i]);
    }
}

// ---------------- build X[t*B+b, 0:2H] = [emb[tok], gf[b]] as bf16 ----------------
__global__ __launch_bounds__(256) void build_x(const int* __restrict__ cap,
                                               const float* __restrict__ emb,
                                               const float* __restrict__ gf,
                                               u16* __restrict__ X) {
    int r = blockIdx.x;                 // r = t*128 + b
    int t = r / B_, b = r % B_;
    int tok = cap[b * T_ + t];
    for (int col = threadIdx.x; col < 2 * H_; col += 256) {
        float v = (col < H_) ? emb[(size_t)tok * H_ + col] : gf[(size_t)b * H_ + (col - H_)];
        X[(size_t)r * (2 * H_) + col] = f2b(v);
    }
}

// ---------------- feat[b,f,h] = area[b,h,f] as bf16 ----------------
__global__ __launch_bounds__(256) void feat_cvt(const float* __restrict__ area,
                                                u16* __restrict__ feat) {
    int idx = blockIdx.x * 256 + threadIdx.x;
    if (idx >= B_ * F_ * H_) return;
    int h = idx & (H_ - 1);
    int bf_ = idx >> 9;
    int f = bf_ % F_, b = bf_ / F_;
    feat[idx] = f2b(area[((size_t)b * H_ + h) * F_ + f]);
}

// ---------------- init h (bf16) and barrier ----------------
__global__ __launch_bounds__(256) void init_hc(const float* __restrict__ h0,
                                               u16* __restrict__ hbf, int* __restrict__ bar) {
    int i = blockIdx.x * 256 + threadIdx.x;
    if (i < B_ * H_) hbf[i] = f2b(h0[i]);
    if (i < 2) bar[i] = 0;
}

// ---------------- device-scope sense-reversing grid barrier ----------------
// All 128 blocks are co-resident by construction (128 <= 256 CUs, 1 block/CU min occ).
__device__ inline void grid_sync(int* bar, int ep) {
    __syncthreads();                       // all stores of this block issued+drained (vmcnt before s_barrier)
    if (threadIdx.x == 0) {
        int old = __hip_atomic_fetch_add(&bar[0], 1, __ATOMIC_ACQ_REL, __HIP_MEMORY_SCOPE_AGENT);
        if (old == NBLK_ - 1) {
            __hip_atomic_store(&bar[0], 0, __ATOMIC_RELAXED, __HIP_MEMORY_SCOPE_AGENT);
            __hip_atomic_fetch_add(&bar[1], 1, __ATOMIC_RELEASE, __HIP_MEMORY_SCOPE_AGENT);
        } else {
            while (__hip_atomic_load(&bar[1], __ATOMIC_ACQUIRE, __HIP_MEMORY_SCOPE_AGENT) < ep)
                __builtin_amdgcn_s_sleep(2);
        }
    }
    __syncthreads();
}

// ================= persistent recurrence kernel: all T=20 steps, 1 barrier/step ======
// Roles per block (bid 0..127):
//   phase 1: (jg = bid>>2) 16 h-cols, (mg = bid&3) 32 batch rows: gates + LSTM
//   phase 3/4: b = bid: ah = h@Wh (MFMA), scores, softmax, attended, Hcat row
__global__ __launch_bounds__(256, 1) void decode_loop(
        const u16* __restrict__ WhhT, const float* __restrict__ Xin,
        const float* __restrict__ c0, const u16* __restrict__ WhT,
        const float* __restrict__ wo, const u16* __restrict__ Vprojb,
        const u16* __restrict__ feat, u16* __restrict__ h0b,
        u16* __restrict__ h1b, u16* __restrict__ Hcat, int* __restrict__ bar) {

    __shared__ __align__(16) u16 hstage[32 * 512];   // 32 KB, XOR-swizzled h quarter
    __shared__ float gl[4 * 32 * 16];                // 8 KB gates
    __shared__ float csh[32 * 16];                   // 2 KB c-state (resident across steps)
    __shared__ float ash[H_];                        // 2 KB ah
    __shared__ float wosh[H_];                       // 2 KB wo
    __shared__ float sc[64];

    const int tid = threadIdx.x;
    const int wave = tid >> 6, lane = tid & 63;
    const int lm = lane & 15, q = lane >> 4;
    const int bid = blockIdx.x;
    const int jg = bid >> 2, mg = bid & 3;           // phase-1 role
    const int b16 = bid & ~15, rr = bid & 15;        // phase-3 role

    // ---- prologue: wo and c-state into LDS ----
    for (int i = tid; i < H_; i += 256) wosh[i] = wo[i];
    #pragma unroll
    for (int ii = 0; ii < 2; ++ii) {
        int idx = tid + ii * 256;
        int lb = idx >> 4, jj = idx & 15;
        csh[idx] = c0[(size_t)(mg * 32 + lb) * H_ + jg * 16 + jj];
    }

    for (int t = 0; t < T_; ++t) {
        const u16* hprev = (t & 1) ? h1b : h0b;
        u16* hnext = (t & 1) ? h0b : h1b;

        // ---- phase 1: stage h quarter (swizzled), gates MFMA, LSTM elementwise ----
        #pragma unroll
        for (int it = 0; it < 8; ++it) {
            int row = it * 4 + wave;                 // local row 0..31, wave-uniform
            int schunk = lane ^ (row & 7);           // pre-swizzled global source (G21)
            load_lds16(hprev + (size_t)(mg * 32 + row) * H_ + schunk * 8,
                       (char*)hstage + row * 1024);
        }
        short8 bfr[16];                              // this wave's gate W_hh frags (16 KB from L2)
        const u16* bp = WhhT + (size_t)(wave * H_ + jg * 16 + lm) * H_ + q * 8;
        #pragma unroll
        for (int kt = 0; kt < 16; ++kt) bfr[kt] = *(const short8*)(bp + kt * 32);
        __syncthreads();                             // drains global_load_lds too

        floatx4 acc0 = {0.f, 0.f, 0.f, 0.f}, acc1 = {0.f, 0.f, 0.f, 0.f};
        #pragma unroll
        for (int kt = 0; kt < 16; ++kt) {
            int ch = kt * 4 + q;
            short8 a0 = *(const short8*)&hstage[(lm << 9) + ((ch ^ (lm & 7)) << 3)];
            short8 a1 = *(const short8*)&hstage[((16 + lm) << 9) + ((ch ^ (lm & 7)) << 3)];
            acc0 = __builtin_amdgcn_mfma_f32_16x16x32_bf16(a0, bfr[kt], acc0, 0, 0, 0);
            acc1 = __builtin_amdgcn_mfma_f32_16x16x32_bf16(a1, bfr[kt], acc1, 0, 0, 0);
        }
        #pragma unroll
        for (int r = 0; r < 4; ++r) {
            gl[wave * 512 + (q * 4 + r) * 16 + lm] = acc0[r];
            gl[wave * 512 + (16 + q * 4 + r) * 16 + lm] = acc1[r];
        }
        __syncthreads();

        #pragma unroll
        for (int ii = 0; ii < 2; ++ii) {
            int idx = tid + ii * 256;
            int lb = idx >> 4, jj = idx & 15;
            int grow = mg * 32 + lb, j = jg * 16 + jj;
            const float* xt = Xin + ((size_t)t * B_ + grow) * (4 * H_);
            float gi = gl[0 * 512 + lb * 16 + jj] + xt[j];
            float gf = gl[1 * 512 + lb * 16 + jj] + xt[H_ + j];
            float gg = gl[2 * 512 + lb * 16 + jj] + xt[2 * H_ + j];
            float go = gl[3 * 512 + lb * 16 + jj] + xt[3 * H_ + j];
            float cn = sigm(gf) * csh[idx] + sigm(gi) * fast_tanh(gg);
            csh[idx] = cn;
            hnext[(size_t)grow * H_ + j] = f2b(sigm(go) * fast_tanh(cn));
        }

        grid_sync(bar, t + 1);   // h(t) fully visible device-wide

        // ---- phase 3: ah = h@Wh via MFMA over the aligned 16-b group (row rr is ours) ----
        floatx4 aacc[8];
        #pragma unroll
        for (int jn = 0; jn < 8; ++jn) aacc[jn] = floatx4{0.f, 0.f, 0.f, 0.f};
        const u16* ap = hnext + (size_t)(b16 + lm) * H_ + q * 8;
        const u16* wp = WhT + (size_t)(wave * 128 + lm) * H_ + q * 8;
        #pragma unroll
        for (int kt = 0; kt < 16; ++kt) {
            short8 av = *(const short8*)(ap + kt * 32);
            #pragma unroll
            for (int jn = 0; jn < 8; ++jn) {
                short8 wv = *(const short8*)(wp + (size_t)jn * 16 * H_ + kt * 32);
                aacc[jn] = __builtin_amdgcn_mfma_f32_16x16x32_bf16(av, wv, aacc[jn], 0, 0, 0);
            }
        }
        if (q == (rr >> 2)) {
            #pragma unroll
            for (int jn = 0; jn < 8; ++jn)
                ash[(wave * 8 + jn) * 16 + lm] = aacc[jn][rr & 3];
        }
        __syncthreads();

        // ---- phase 4: scores, softmax, attended, Hcat (b = bid) ----
        for (int f = wave; f < F_; f += 4) {
            const u16* vp = Vprojb + ((size_t)bid * F_ + f) * H_ + lane * 8;
            short8 vv = *(const short8*)vp;
            float s = 0.f;
            #pragma unroll
            for (int e = 0; e < 8; ++e) {
                int h = lane * 8 + e;
                s += wosh[h] * fast_tanh(b2f((u16)vv[e]) + ash[h]);
            }
            #pragma unroll
            for (int off = 32; off; off >>= 1) s += __shfl_xor(s, off);
            if (lane == 0) sc[f] = s;
        }
        __syncthreads();
        if (tid < 64) {
            float v = (tid < F_) ? sc[tid] : -1e30f;
            float m = v;
            #pragma unroll
            for (int off = 32; off; off >>= 1) m = fmaxf(m, __shfl_xor(m, off));
            float e = (tid < F_) ? __expf(v - m) : 0.f;
            float sum = e;
            #pragma unroll
            for (int off = 32; off; off >>= 1) sum += __shfl_xor(sum, off);
            if (tid < F_) sc[tid] = e / sum;
        }
        __syncthreads();
        const size_t rowo = ((size_t)bid * T_ + t) * (2 * H_);
        for (int h = tid; h < H_; h += 256) {
            const u16* fp = feat + (size_t)bid * F_ * H_ + h;
            float acc = 0.f;
            #pragma unroll
            for (int f = 0; f < F_; ++f) acc += b2f(fp[(size_t)f * H_]) * sc[f];
            Hcat[rowo + h] = hnext[(size_t)bid * H_ + h];
            Hcat[rowo + H_ + h] = f2b(acc);
        }
        // No trailing sync needed: phase1(t+1) writes the OTHER h buffer and only
        // touches hstage/gl (not read by phase 3/4), with its own __syncthreads.
    }
}

// ========== m97-style bf16 MFMA GEMM: C[M,N] = A[M,K] @ Bt[N,K]^T (+bias) ==========
template <int WRITE_BF16>
__global__ __launch_bounds__(256) void gemm2(const u16* __restrict__ A, int lda,
                                             const u16* __restrict__ Bt, int ldb,
                                             void* __restrict__ Cout, int ldc,
                                             const float* __restrict__ bias1,
                                             const float* __restrict__ bias2,
                                             int M, int N, int K) {
    __shared__ __align__(16) u16 As[128 * 32];
    __shared__ __align__(16) u16 Bs[128 * 32];
    const int tid = threadIdx.x, wave = tid >> 6, lane = tid & 63;
    const int wr = wave >> 1, wc = wave & 1;
    const int lm = lane & 15, q = lane >> 4;
    const int m0 = blockIdx.x * 128, n0 = blockIdx.y * 128;

    const int off = wave * 1024 + lane * 16;
    const int r0 = off >> 6;
    const int c0 = (off & 63) >> 1;

    const u16* gA0 = A + (size_t)(m0 + r0) * lda + c0;
    const u16* gA1 = A + (size_t)(m0 + r0 + 64) * lda + c0;
    int nb0 = n0 + r0;      if (nb0 > N - 1) nb0 = N - 1;
    int nb1 = n0 + r0 + 64; if (nb1 > N - 1) nb1 = N - 1;
    const u16* gB0 = Bt + (size_t)nb0 * ldb + c0;
    const u16* gB1 = Bt + (size_t)nb1 * ldb + c0;
    char* lA0 = (char*)As + wave * 1024;
    char* lA1 = (char*)As + 4096 + wave * 1024;
    char* lB0 = (char*)Bs + wave * 1024;
    char* lB1 = (char*)Bs + 4096 + wave * 1024;

    floatx4 acc[4][4];
    #pragma unroll
    for (int i = 0; i < 4; ++i)
        #pragma unroll
        for (int j = 0; j < 4; ++j) acc[i][j] = floatx4{0.f, 0.f, 0.f, 0.f};

    const int nkt = K >> 5;
    for (int kt = 0; kt < nkt; ++kt) {
        const int ko = kt * 32;
        load_lds16(gA0 + ko, lA0);
        load_lds16(gA1 + ko, lA1);
        load_lds16(gB0 + ko, lB0);
        load_lds16(gB1 + ko, lB1);
        __syncthreads();
        short8 af[4], bf[4];
        #pragma unroll
        for (int i = 0; i < 4; ++i)
            af[i] = *(const short8*)&As[(wr * 64 + i * 16 + lm) * 32 + q * 8];
        #pragma unroll
        for (int j = 0; j < 4; ++j)
            bf[j] = *(const short8*)&Bs[(wc * 64 + j * 16 + lm) * 32 + q * 8];
        #pragma unroll
        for (int i = 0; i < 4; ++i)
            #pragma unroll
            for (int j = 0; j < 4; ++j)
                acc[i][j] = __builtin_amdgcn_mfma_f32_16x16x32_bf16(af[i], bf[j], acc[i][j], 0, 0, 0);
        __syncthreads();
    }

    #pragma unroll
    for (int i = 0; i < 4; ++i) {
        const int row = m0 + wr * 64 + i * 16 + q * 4;
        #pragma unroll
        for (int j = 0; j < 4; ++j) {
            const int col = n0 + wc * 64 + j * 16 + lm;
            if (col < N) {
                #pragma unroll
                for (int r = 0; r < 4; ++r) {
                    float v = acc[i][j][r];
                    if (bias1) v += bias1[col];
                    if (bias2) v += bias2[col];
                    if (WRITE_BF16) ((u16*)Cout)[(size_t)(row + r) * ldc + col] = f2b(v);
                    else            ((float*)Cout)[(size_t)(row + r) * ldc + col] = v;
                }
            }
        }
    }
}

extern "C" void kernel_launch(void* const* d_in, const int* in_sizes, int n_in,
                              void* d_out, int out_size, void* d_ws, size_t ws_size,
                              hipStream_t stream) {
    const int*   cap   = (const int*)d_in[0];
    const float* gf    = (const float*)d_in[1];
    const float* area  = (const float*)d_in[2];
    const float* h0    = (const float*)d_in[3];
    const float* c0    = (const float*)d_in[4];
    const float* emb   = (const float*)d_in[5];
    const float* W_ih  = (const float*)d_in[6];
    const float* W_hh  = (const float*)d_in[7];
    const float* b_ih  = (const float*)d_in[8];
    const float* b_hh  = (const float*)d_in[9];
    const float* Wv    = (const float*)d_in[10];
    const float* Wh    = (const float*)d_in[11];
    const float* wo    = (const float*)d_in[12];
    const float* W_out = (const float*)d_in[13];
    const float* b_out = (const float*)d_in[14];
    float* out = (float*)d_out;

    char* p = (char*)d_ws;
    auto alloc = [&](size_t bytes) {
        char* q = p;
        p += (bytes + 255) & ~(size_t)255;
        return q;
    };
    u16*   X      = (u16*)alloc((size_t)T_ * B_ * 2 * H_ * 2);     // [2560,1024]
    u16*   WihT   = (u16*)alloc((size_t)4 * H_ * 2 * H_ * 2);      // [2048,1024]
    u16*   WhhT   = (u16*)alloc((size_t)4 * H_ * H_ * 2);          // [2048,512]
    u16*   WvT    = (u16*)alloc((size_t)H_ * H_ * 2);              // [512,512]
    u16*   WhT    = (u16*)alloc((size_t)H_ * H_ * 2);              // [512,512]
    u16*   WoutT  = (u16*)alloc((size_t)V_ * 2 * H_ * 2);          // [10000,1024]
    u16*   feat   = (u16*)alloc((size_t)B_ * F_ * H_ * 2);         // [6272,512]
    float* Xin    = (float*)alloc((size_t)T_ * B_ * 4 * H_ * 4);   // [2560,2048] f32
    u16*   Vprojb = (u16*)alloc((size_t)B_ * F_ * H_ * 2);         // [6272,512] bf16
    int*   bar    = (int*)alloc(256);
    u16*   hbf0   = (u16*)alloc((size_t)B_ * H_ * 2);
    u16*   hbf1   = (u16*)alloc((size_t)B_ * H_ * 2);
    u16*   Hcat   = (u16*)alloc((size_t)B_ * T_ * 2 * H_ * 2);     // [2560,1024]

    dim3 tb(32, 8);
    transpose_cvt<<<dim3(4 * H_ / 32, 2 * H_ / 32), tb, 0, stream>>>(W_ih, WihT, 2 * H_, 4 * H_);
    transpose_cvt<<<dim3(4 * H_ / 32, H_ / 32), tb, 0, stream>>>(W_hh, WhhT, H_, 4 * H_);
    transpose_cvt<<<dim3(H_ / 32, H_ / 32), tb, 0, stream>>>(Wv, WvT, H_, H_);
    transpose_cvt<<<dim3(H_ / 32, H_ / 32), tb, 0, stream>>>(Wh, WhT, H_, H_);
    transpose_cvt<<<dim3((V_ + 31) / 32, 2 * H_ / 32), tb, 0, stream>>>(W_out, WoutT, 2 * H_, V_);
    build_x<<<T_ * B_, 256, 0, stream>>>(cap, emb, gf, X);
    feat_cvt<<<(B_ * F_ * H_ + 255) / 256, 256, 0, stream>>>(area, feat);
    init_hc<<<(B_ * H_ + 255) / 256, 256, 0, stream>>>(h0, hbf0, bar);

    // Xin = X @ W_ih + b_ih + b_hh   [2560,2048] f32
    gemm2<0><<<dim3(T_ * B_ / 128, 4 * H_ / 128), 256, 0, stream>>>(
        X, 2 * H_, WihT, 2 * H_, Xin, 4 * H_, b_ih, b_hh, T_ * B_, 4 * H_, 2 * H_);
    // Vproj = feat @ Wv  -> bf16 [6272,512]
    gemm2<1><<<dim3(B_ * F_ / 128, H_ / 128), 256, 0, stream>>>(
        feat, H_, WvT, H_, Vprojb, H_, nullptr, nullptr, B_ * F_, H_, H_);

    // Entire T=20 recurrence in ONE persistent kernel (replaces 40 launches)
    decode_loop<<<NBLK_, 256, 0, stream>>>(
        WhhT, Xin, c0, WhT, wo, Vprojb, feat, hbf0, hbf1, Hcat, bar);

    // out = Hcat @ W_out + b_out   [2560,10000] f32
    gemm2<0><<<dim3(T_ * B_ / 128, (V_ + 127) / 128), 256, 0, stream>>>(
        Hcat, 2 * H_, WoutT, 2 * H_, out, V_, b_out, nullptr, T_ * B_, V_, 2 * H_);
}

// Round 3
// 666.296 us; speedup vs baseline: 2.6832x; 2.6832x over previous
//
#include <hip/hip_runtime.h>

#define B_ 128
#define T_ 20
#define V_ 10000
#define H_ 512
#define F_ 49
#define NBLK_ 128

typedef unsigned short u16;
typedef __attribute__((ext_vector_type(8))) short short8;
typedef __attribute__((ext_vector_type(4))) float floatx4;

#define GLOBAL_AS __attribute__((address_space(1)))
#define LDS_AS    __attribute__((address_space(3)))

__device__ inline void load_lds16(const void* g, void* l) {
    __builtin_amdgcn_global_load_lds((const GLOBAL_AS void*)g, (LDS_AS void*)l, 16, 0, 0);
}

// fp32 -> bf16 round-to-nearest-even
__device__ inline u16 f2b(float v) {
    unsigned u = __builtin_bit_cast(unsigned, v);
    unsigned rounding = 0x7FFFu + ((u >> 16) & 1u);
    return (u16)((u + rounding) >> 16);
}
__device__ inline float b2f(u16 h) {
    unsigned u = ((unsigned)h) << 16;
    return __builtin_bit_cast(float, u);
}
__device__ inline float fast_tanh(float x) {
    return 1.f - 2.f / (__expf(2.f * x) + 1.f);
}
__device__ inline float sigm(float x) { return 1.f / (1.f + __expf(-x)); }

// ---------------- transpose + convert: src[K,N] f32 -> dst[N,K] bf16 ----------------
__global__ __launch_bounds__(256) void transpose_cvt(const float* __restrict__ src,
                                                     u16* __restrict__ dst, int K, int N) {
    __shared__ float tile[32][33];
    int n0 = blockIdx.x * 32, k0 = blockIdx.y * 32;
    int tx = threadIdx.x, ty = threadIdx.y;   // 32 x 8
    #pragma unroll
    for (int i = 0; i < 32; i += 8) {
        int k = k0 + ty + i, n = n0 + tx;
        tile[ty + i][tx] = (k < K && n < N) ? src[(size_t)k * N + n] : 0.f;
    }
    __syncthreads();
    #pragma unroll
    for (int i = 0; i < 32; i += 8) {
        int n = n0 + ty + i, k = k0 + tx;
        if (n < N && k < K) dst[(size_t)n * K + k] = f2b(tile[tx][ty + i]);
    }
}

// ---------------- build X[t*B+b, 0:2H] = [emb[tok], gf[b]] as bf16 ----------------
__global__ __launch_bounds__(256) void build_x(const int* __restrict__ cap,
                                               const float* __restrict__ emb,
                                               const float* __restrict__ gf,
                                               u16* __restrict__ X) {
    int r = blockIdx.x;                 // r = t*128 + b
    int t = r / B_, b = r % B_;
    int tok = cap[b * T_ + t];
    for (int col = threadIdx.x; col < 2 * H_; col += 256) {
        float v = (col < H_) ? emb[(size_t)tok * H_ + col] : gf[(size_t)b * H_ + (col - H_)];
        X[(size_t)r * (2 * H_) + col] = f2b(v);
    }
}

// ---------------- feat[b,f,h] = area[b,h,f] as bf16 ----------------
__global__ __launch_bounds__(256) void feat_cvt(const float* __restrict__ area,
                                                u16* __restrict__ feat) {
    int idx = blockIdx.x * 256 + threadIdx.x;
    if (idx >= B_ * F_ * H_) return;
    int h = idx & (H_ - 1);
    int bf_ = idx >> 9;
    int f = bf_ % F_, b = bf_ / F_;
    feat[idx] = f2b(area[((size_t)b * H_ + h) * F_ + f]);
}

// ---------------- init Hall[0] = h0 (bf16); zero barrier lines ----------------
__global__ __launch_bounds__(256) void init_hc(const float* __restrict__ h0,
                                               u16* __restrict__ Hall, int* __restrict__ bar) {
    int i = blockIdx.x * 256 + threadIdx.x;
    if (i < B_ * H_) Hall[i] = f2b(h0[i]);
    if (i < 64) bar[i] = 0;
}

// ---------------- grid barrier: relaxed poll, single acquire on exit ----------------
// bar[0] = arrival counter; bar[32] = epoch (separate 128-B line).
__device__ inline void grid_sync(int* bar, int ep) {
    __syncthreads();   // emits s_waitcnt vmcnt(0): all waves' stores have reached L2
    if (threadIdx.x == 0) {
        int old = __hip_atomic_fetch_add(&bar[0], 1, __ATOMIC_ACQ_REL, __HIP_MEMORY_SCOPE_AGENT);
        if (old == NBLK_ - 1) {
            __hip_atomic_store(&bar[0], 0, __ATOMIC_RELAXED, __HIP_MEMORY_SCOPE_AGENT);
            __hip_atomic_store(&bar[32], ep, __ATOMIC_RELEASE, __HIP_MEMORY_SCOPE_AGENT);
        } else {
            // RELAXED poll: agent-scope atomic loads are coherent (sc1) but do NOT
            // invalidate L2 each iteration (the previous version's ACQUIRE poll did).
            while (__hip_atomic_load(&bar[32], __ATOMIC_RELAXED, __HIP_MEMORY_SCOPE_AGENT) < ep)
                __builtin_amdgcn_s_sleep(1);
            (void)__hip_atomic_load(&bar[32], __ATOMIC_ACQUIRE, __HIP_MEMORY_SCOPE_AGENT);
        }
    }
    __syncthreads();
}

// ================= persistent LSTM-only recurrence: 1 barrier/step =================
// 128 blocks: jg = bid>>2 (16 h-cols), mg = bid&3 (32 batch rows).
// WhhT slice + c-state live in LDS for all 20 steps (immune to L2 invalidation).
// Attention is deferred entirely (it does not feed back into the recurrence).
__global__ __launch_bounds__(256, 1) void decode_loop(
        const u16* __restrict__ WhhT, const float* __restrict__ Xin,
        const float* __restrict__ c0, u16* __restrict__ Hall,
        u16* __restrict__ Hcat, int* __restrict__ bar) {

    __shared__ __align__(16) u16 Whs[64 * 512];      // 64 KB: row r = g*16+lr, XOR-swizzled
    __shared__ __align__(16) u16 hstage[32 * 512];   // 32 KB, XOR-swizzled h slice
    __shared__ float gl[4 * 32 * 16];                // 8 KB gates
    __shared__ float csh[32 * 16];                   // 2 KB c-state (resident)

    const int tid = threadIdx.x;
    const int wave = tid >> 6, lane = tid & 63;
    const int lm = lane & 15, q = lane >> 4;
    const int bid = blockIdx.x;
    const int jg = bid >> 2, mg = bid & 3;

    // ---- prologue: stage WhhT slice (64 rows x 512) swizzled; c0 into LDS ----
    #pragma unroll
    for (int i = 0; i < 16; ++i) {
        int row = i * 4 + wave;                      // 0..63, wave-uniform
        int g = row >> 4, lr = row & 15;
        int grow = g * H_ + jg * 16 + lr;            // WhhT row (gate col index)
        load_lds16(WhhT + (size_t)grow * H_ + (size_t)(lane ^ (row & 7)) * 8,
                   (char*)Whs + row * 1024);
    }
    #pragma unroll
    for (int ii = 0; ii < 2; ++ii) {
        int idx = tid + ii * 256;
        int lb = idx >> 4, jj = idx & 15;
        csh[idx] = c0[(size_t)(mg * 32 + lb) * H_ + jg * 16 + jj];
    }

    for (int t = 0; t < T_; ++t) {
        const u16* hprev = Hall + (size_t)t * B_ * H_;
        u16* hnext = Hall + (size_t)(t + 1) * B_ * H_;

        // ---- stage h slice (32 rows), pre-swizzled source ----
        #pragma unroll
        for (int it = 0; it < 8; ++it) {
            int row = it * 4 + wave;                 // 0..31, wave-uniform
            load_lds16(hprev + (size_t)(mg * 32 + row) * H_ + (size_t)(lane ^ (row & 7)) * 8,
                       (char*)hstage + row * 1024);
        }
        __syncthreads();                             // drains global_load_lds (prologue too)

        // ---- gates MFMA: wave g computes its gate's 32x16 tile ----
        floatx4 acc0 = {0.f, 0.f, 0.f, 0.f}, acc1 = {0.f, 0.f, 0.f, 0.f};
        #pragma unroll
        for (int kt = 0; kt < 16; ++kt) {
            int ch = kt * 4 + q;
            short8 a0 = *(const short8*)&hstage[(lm << 9) + ((ch ^ (lm & 7)) << 3)];
            short8 a1 = *(const short8*)&hstage[((16 + lm) << 9) + ((ch ^ (lm & 7)) << 3)];
            short8 bb = *(const short8*)&Whs[((wave * 16 + lm) << 9) + ((ch ^ (lm & 7)) << 3)];
            acc0 = __builtin_amdgcn_mfma_f32_16x16x32_bf16(a0, bb, acc0, 0, 0, 0);
            acc1 = __builtin_amdgcn_mfma_f32_16x16x32_bf16(a1, bb, acc1, 0, 0, 0);
        }
        #pragma unroll
        for (int r = 0; r < 4; ++r) {
            gl[wave * 512 + (q * 4 + r) * 16 + lm] = acc0[r];
            gl[wave * 512 + (16 + q * 4 + r) * 16 + lm] = acc1[r];
        }
        __syncthreads();

        // ---- LSTM elementwise; write h into Hall[t+1] AND Hcat left half ----
        #pragma unroll
        for (int ii = 0; ii < 2; ++ii) {
            int idx = tid + ii * 256;
            int lb = idx >> 4, jj = idx & 15;
            int grow = mg * 32 + lb, j = jg * 16 + jj;
            const float* xt = Xin + ((size_t)t * B_ + grow) * (4 * H_);
            float gi = gl[0 * 512 + lb * 16 + jj] + xt[j];
            float gf = gl[1 * 512 + lb * 16 + jj] + xt[H_ + j];
            float gg = gl[2 * 512 + lb * 16 + jj] + xt[2 * H_ + j];
            float go = gl[3 * 512 + lb * 16 + jj] + xt[3 * H_ + j];
            float cn = sigm(gf) * csh[idx] + sigm(gi) * fast_tanh(gg);
            csh[idx] = cn;
            u16 hb = f2b(sigm(go) * fast_tanh(cn));
            hnext[(size_t)grow * H_ + j] = hb;
            Hcat[((size_t)grow * T_ + t) * (2 * H_) + j] = hb;
        }

        grid_sync(bar, t + 1);   // publish h(t) device-wide
    }
}

// ================= deferred attention: per (b, t-half), all data staged in LDS ======
// grid 256: b = bid>>1, t in [th*10, th*10+10). Reads ahbuf (f32) from the batched GEMM.
__global__ __launch_bounds__(256) void attn_post(
        const float* __restrict__ ahbuf, const u16* __restrict__ Vprojb,
        const u16* __restrict__ feat, const float* __restrict__ wo,
        u16* __restrict__ Hcat) {
    __shared__ __align__(16) u16 Vsh[F_ * H_];   // 49 KB
    __shared__ __align__(16) u16 fsh[F_ * H_];   // 49 KB
    __shared__ float ash[H_];
    __shared__ float wosh[H_];
    __shared__ float sc[64];

    const int tid = threadIdx.x;
    const int wave = tid >> 6, lane = tid & 63;
    const int b = blockIdx.x >> 1, th = blockIdx.x & 1;

    const short8* vsrc = (const short8*)(Vprojb + (size_t)b * F_ * H_);
    const short8* fsrc = (const short8*)(feat + (size_t)b * F_ * H_);
    for (int i = tid; i < F_ * H_ / 8; i += 256) {
        ((short8*)Vsh)[i] = vsrc[i];
        ((short8*)fsh)[i] = fsrc[i];
    }
    for (int i = tid; i < H_; i += 256) wosh[i] = wo[i];
    __syncthreads();

    for (int t = th * (T_ / 2); t < (th + 1) * (T_ / 2); ++t) {
        for (int i = tid; i < H_; i += 256)
            ash[i] = ahbuf[((size_t)t * B_ + b) * H_ + i];
        __syncthreads();

        // scores[f] = sum_h wo[h] * tanh(Vproj[b,f,h] + ah[h])
        for (int f = wave; f < F_; f += 4) {
            short8 vv = *(const short8*)&Vsh[f * H_ + lane * 8];
            float s = 0.f;
            #pragma unroll
            for (int e = 0; e < 8; ++e) {
                int h = lane * 8 + e;
                s += wosh[h] * fast_tanh(b2f((u16)vv[e]) + ash[h]);
            }
            #pragma unroll
            for (int off = 32; off; off >>= 1) s += __shfl_xor(s, off);
            if (lane == 0) sc[f] = s;
        }
        __syncthreads();

        if (tid < 64) {
            float v = (tid < F_) ? sc[tid] : -1e30f;
            float m = v;
            #pragma unroll
            for (int off = 32; off; off >>= 1) m = fmaxf(m, __shfl_xor(m, off));
            float e = (tid < F_) ? __expf(v - m) : 0.f;
            float sum = e;
            #pragma unroll
            for (int off = 32; off; off >>= 1) sum += __shfl_xor(sum, off);
            if (tid < F_) sc[tid] = e / sum;
        }
        __syncthreads();

        const size_t rowo = ((size_t)b * T_ + t) * (2 * H_);
        for (int h = tid; h < H_; h += 256) {
            float acc = 0.f;
            #pragma unroll
            for (int f = 0; f < F_; ++f) acc += b2f(fsh[f * H_ + h]) * sc[f];
            Hcat[rowo + H_ + h] = f2b(acc);
        }
        __syncthreads();   // sc/ash reused next t
    }
}

// ========== m97-style bf16 MFMA GEMM: C[M,N] = A[M,K] @ Bt[N,K]^T (+bias) ==========
template <int WRITE_BF16>
__global__ __launch_bounds__(256) void gemm2(const u16* __restrict__ A, int lda,
                                             const u16* __restrict__ Bt, int ldb,
                                             void* __restrict__ Cout, int ldc,
                                             const float* __restrict__ bias1,
                                             const float* __restrict__ bias2,
                                             int M, int N, int K) {
    __shared__ __align__(16) u16 As[128 * 32];
    __shared__ __align__(16) u16 Bs[128 * 32];
    const int tid = threadIdx.x, wave = tid >> 6, lane = tid & 63;
    const int wr = wave >> 1, wc = wave & 1;
    const int lm = lane & 15, q = lane >> 4;
    const int m0 = blockIdx.x * 128, n0 = blockIdx.y * 128;

    const int off = wave * 1024 + lane * 16;
    const int r0 = off >> 6;
    const int c0 = (off & 63) >> 1;

    const u16* gA0 = A + (size_t)(m0 + r0) * lda + c0;
    const u16* gA1 = A + (size_t)(m0 + r0 + 64) * lda + c0;
    int nb0 = n0 + r0;      if (nb0 > N - 1) nb0 = N - 1;
    int nb1 = n0 + r0 + 64; if (nb1 > N - 1) nb1 = N - 1;
    const u16* gB0 = Bt + (size_t)nb0 * ldb + c0;
    const u16* gB1 = Bt + (size_t)nb1 * ldb + c0;
    char* lA0 = (char*)As + wave * 1024;
    char* lA1 = (char*)As + 4096 + wave * 1024;
    char* lB0 = (char*)Bs + wave * 1024;
    char* lB1 = (char*)Bs + 4096 + wave * 1024;

    floatx4 acc[4][4];
    #pragma unroll
    for (int i = 0; i < 4; ++i)
        #pragma unroll
        for (int j = 0; j < 4; ++j) acc[i][j] = floatx4{0.f, 0.f, 0.f, 0.f};

    const int nkt = K >> 5;
    for (int kt = 0; kt < nkt; ++kt) {
        const int ko = kt * 32;
        load_lds16(gA0 + ko, lA0);
        load_lds16(gA1 + ko, lA1);
        load_lds16(gB0 + ko, lB0);
        load_lds16(gB1 + ko, lB1);
        __syncthreads();
        short8 af[4], bf[4];
        #pragma unroll
        for (int i = 0; i < 4; ++i)
            af[i] = *(const short8*)&As[(wr * 64 + i * 16 + lm) * 32 + q * 8];
        #pragma unroll
        for (int j = 0; j < 4; ++j)
            bf[j] = *(const short8*)&Bs[(wc * 64 + j * 16 + lm) * 32 + q * 8];
        #pragma unroll
        for (int i = 0; i < 4; ++i)
            #pragma unroll
            for (int j = 0; j < 4; ++j)
                acc[i][j] = __builtin_amdgcn_mfma_f32_16x16x32_bf16(af[i], bf[j], acc[i][j], 0, 0, 0);
        __syncthreads();
    }

    #pragma unroll
    for (int i = 0; i < 4; ++i) {
        const int row = m0 + wr * 64 + i * 16 + q * 4;
        #pragma unroll
        for (int j = 0; j < 4; ++j) {
            const int col = n0 + wc * 64 + j * 16 + lm;
            if (col < N) {
                #pragma unroll
                for (int r = 0; r < 4; ++r) {
                    float v = acc[i][j][r];
                    if (bias1) v += bias1[col];
                    if (bias2) v += bias2[col];
                    if (WRITE_BF16) ((u16*)Cout)[(size_t)(row + r) * ldc + col] = f2b(v);
                    else            ((float*)Cout)[(size_t)(row + r) * ldc + col] = v;
                }
            }
        }
    }
}

extern "C" void kernel_launch(void* const* d_in, const int* in_sizes, int n_in,
                              void* d_out, int out_size, void* d_ws, size_t ws_size,
                              hipStream_t stream) {
    const int*   cap   = (const int*)d_in[0];
    const float* gf    = (const float*)d_in[1];
    const float* area  = (const float*)d_in[2];
    const float* h0    = (const float*)d_in[3];
    const float* c0    = (const float*)d_in[4];
    const float* emb   = (const float*)d_in[5];
    const float* W_ih  = (const float*)d_in[6];
    const float* W_hh  = (const float*)d_in[7];
    const float* b_ih  = (const float*)d_in[8];
    const float* b_hh  = (const float*)d_in[9];
    const float* Wv    = (const float*)d_in[10];
    const float* Wh    = (const float*)d_in[11];
    const float* wo    = (const float*)d_in[12];
    const float* W_out = (const float*)d_in[13];
    const float* b_out = (const float*)d_in[14];
    float* out = (float*)d_out;

    char* p = (char*)d_ws;
    auto alloc = [&](size_t bytes) {
        char* q = p;
        p += (bytes + 255) & ~(size_t)255;
        return q;
    };
    u16*   X      = (u16*)alloc((size_t)T_ * B_ * 2 * H_ * 2);     // [2560,1024]
    u16*   WihT   = (u16*)alloc((size_t)4 * H_ * 2 * H_ * 2);      // [2048,1024]
    u16*   WhhT   = (u16*)alloc((size_t)4 * H_ * H_ * 2);          // [2048,512]
    u16*   WvT    = (u16*)alloc((size_t)H_ * H_ * 2);              // [512,512]
    u16*   WhT    = (u16*)alloc((size_t)H_ * H_ * 2);              // [512,512]
    u16*   WoutT  = (u16*)alloc((size_t)V_ * 2 * H_ * 2);          // [10000,1024]
    u16*   feat   = (u16*)alloc((size_t)B_ * F_ * H_ * 2);         // [6272,512]
    float* Xin    = (float*)alloc((size_t)T_ * B_ * 4 * H_ * 4);   // [2560,2048] f32
    u16*   Vprojb = (u16*)alloc((size_t)B_ * F_ * H_ * 2);         // [6272,512] bf16
    float* ahbuf  = (float*)alloc((size_t)T_ * B_ * H_ * 4);       // [2560,512] f32
    u16*   Hall   = (u16*)alloc((size_t)(T_ + 1) * B_ * H_ * 2);   // [21,128,512]
    int*   bar    = (int*)alloc(256);
    u16*   Hcat   = (u16*)alloc((size_t)B_ * T_ * 2 * H_ * 2);     // [2560,1024]

    dim3 tb(32, 8);
    transpose_cvt<<<dim3(4 * H_ / 32, 2 * H_ / 32), tb, 0, stream>>>(W_ih, WihT, 2 * H_, 4 * H_);
    transpose_cvt<<<dim3(4 * H_ / 32, H_ / 32), tb, 0, stream>>>(W_hh, WhhT, H_, 4 * H_);
    transpose_cvt<<<dim3(H_ / 32, H_ / 32), tb, 0, stream>>>(Wv, WvT, H_, H_);
    transpose_cvt<<<dim3(H_ / 32, H_ / 32), tb, 0, stream>>>(Wh, WhT, H_, H_);
    transpose_cvt<<<dim3((V_ + 31) / 32, 2 * H_ / 32), tb, 0, stream>>>(W_out, WoutT, 2 * H_, V_);
    build_x<<<T_ * B_, 256, 0, stream>>>(cap, emb, gf, X);
    feat_cvt<<<(B_ * F_ * H_ + 255) / 256, 256, 0, stream>>>(area, feat);
    init_hc<<<(B_ * H_ + 255) / 256, 256, 0, stream>>>(h0, Hall, bar);

    // Xin = X @ W_ih + b_ih + b_hh   [2560,2048] f32
    gemm2<0><<<dim3(T_ * B_ / 128, 4 * H_ / 128), 256, 0, stream>>>(
        X, 2 * H_, WihT, 2 * H_, Xin, 4 * H_, b_ih, b_hh, T_ * B_, 4 * H_, 2 * H_);
    // Vproj = feat @ Wv  -> bf16 [6272,512]
    gemm2<1><<<dim3(B_ * F_ / 128, H_ / 128), 256, 0, stream>>>(
        feat, H_, WvT, H_, Vprojb, H_, nullptr, nullptr, B_ * F_, H_, H_);

    // LSTM-only persistent recurrence (attention deferred)
    decode_loop<<<NBLK_, 256, 0, stream>>>(WhhT, Xin, c0, Hall, Hcat, bar);

    // ah_all = Hall[1..T] @ Wh   [2560,512] f32 (batched over all t)
    gemm2<0><<<dim3(T_ * B_ / 128, H_ / 128), 256, 0, stream>>>(
        Hall + (size_t)B_ * H_, H_, WhT, H_, ahbuf, H_, nullptr, nullptr, T_ * B_, H_, H_);

    // scores/softmax/attended for all (b,t) in parallel
    attn_post<<<2 * B_, 256, 0, stream>>>(ahbuf, Vprojb, feat, wo, Hcat);

    // out = Hcat @ W_out + b_out   [2560,10000] f32
    gemm2<0><<<dim3(T_ * B_ / 128, (V_ + 127) / 128), 256, 0, stream>>>(
        Hcat, 2 * H_, WoutT, 2 * H_, out, V_, b_out, nullptr, T_ * B_, V_, 2 * H_);
}

// Round 4
// 652.560 us; speedup vs baseline: 2.7397x; 1.0210x over previous
//
#include <hip/hip_runtime.h>

#define B_ 128
#define T_ 20
#define V_ 10000
#define H_ 512
#define F_ 49
#define NBLK_ 128

typedef unsigned short u16;
typedef __attribute__((ext_vector_type(8))) short short8;
typedef __attribute__((ext_vector_type(4))) float floatx4;

#define GLOBAL_AS __attribute__((address_space(1)))
#define LDS_AS    __attribute__((address_space(3)))

__device__ inline void load_lds16(const void* g, void* l) {
    __builtin_amdgcn_global_load_lds((const GLOBAL_AS void*)g, (LDS_AS void*)l, 16, 0, 0);
}

// fp32 -> bf16 round-to-nearest-even
__device__ inline u16 f2b(float v) {
    unsigned u = __builtin_bit_cast(unsigned, v);
    unsigned rounding = 0x7FFFu + ((u >> 16) & 1u);
    return (u16)((u + rounding) >> 16);
}
__device__ inline float b2f(u16 h) {
    unsigned u = ((unsigned)h) << 16;
    return __builtin_bit_cast(float, u);
}
__device__ inline float fast_tanh(float x) {
    return 1.f - 2.f / (__expf(2.f * x) + 1.f);
}
__device__ inline float sigm(float x) { return 1.f / (1.f + __expf(-x)); }

// ---------------- transpose + convert: src[K,N] f32 -> dst[N,K] bf16 ----------------
__global__ __launch_bounds__(256) void transpose_cvt(const float* __restrict__ src,
                                                     u16* __restrict__ dst, int K, int N) {
    __shared__ float tile[32][33];
    int n0 = blockIdx.x * 32, k0 = blockIdx.y * 32;
    int tx = threadIdx.x, ty = threadIdx.y;   // 32 x 8
    #pragma unroll
    for (int i = 0; i < 32; i += 8) {
        int k = k0 + ty + i, n = n0 + tx;
        tile[ty + i][tx] = (k < K && n < N) ? src[(size_t)k * N + n] : 0.f;
    }
    __syncthreads();
    #pragma unroll
    for (int i = 0; i < 32; i += 8) {
        int n = n0 + ty + i, k = k0 + tx;
        if (n < N && k < K) dst[(size_t)n * K + k] = f2b(tile[tx][ty + i]);
    }
}

// ---------------- build X[t*B+b, 0:2H] = [emb[tok], gf[b]] as bf16 ----------------
__global__ __launch_bounds__(256) void build_x(const int* __restrict__ cap,
                                               const float* __restrict__ emb,
                                               const float* __restrict__ gf,
                                               u16* __restrict__ X) {
    int r = blockIdx.x;                 // r = t*128 + b
    int t = r / B_, b = r % B_;
    int tok = cap[b * T_ + t];
    for (int col = threadIdx.x; col < 2 * H_; col += 256) {
        float v = (col < H_) ? emb[(size_t)tok * H_ + col] : gf[(size_t)b * H_ + (col - H_)];
        X[(size_t)r * (2 * H_) + col] = f2b(v);
    }
}

// ---------------- feat[b,f,h] = area[b,h,f] as bf16 ----------------
__global__ __launch_bounds__(256) void feat_cvt(const float* __restrict__ area,
                                                u16* __restrict__ feat) {
    int idx = blockIdx.x * 256 + threadIdx.x;
    if (idx >= B_ * F_ * H_) return;
    int h = idx & (H_ - 1);
    int bf_ = idx >> 9;
    int f = bf_ % F_, b = bf_ / F_;
    feat[idx] = f2b(area[((size_t)b * H_ + h) * F_ + f]);
}

// ---------------- init Hall[0] = h0 (bf16); zero barrier lines ----------------
__global__ __launch_bounds__(256) void init_hc(const float* __restrict__ h0,
                                               u16* __restrict__ Hall, int* __restrict__ bar) {
    int i = blockIdx.x * 256 + threadIdx.x;
    if (i < B_ * H_) Hall[i] = f2b(h0[i]);
    if (i < 256) bar[i] = 0;
}

// ---------------- per-mg grid barrier: 32 blocks, monotonic counter ----------------
// base[0] = arrival counter; base[32] = epoch (separate 128-B line).
// Monotonic: at epoch ep (1-based) counter rises from (ep-1)*32 to ep*32 — no resets.
__device__ inline void grid_sync_mg(int* base, int ep) {
    __syncthreads();   // drains vmcnt: all waves' h-stores complete before arrival
    if (threadIdx.x == 0) {
        int old = __hip_atomic_fetch_add(&base[0], 1, __ATOMIC_ACQ_REL, __HIP_MEMORY_SCOPE_AGENT);
        if (old == ep * 32 - 1)
            __hip_atomic_store(&base[32], ep, __ATOMIC_RELEASE, __HIP_MEMORY_SCOPE_AGENT);
        // RELAXED poll (no per-iteration L2 invalidate), one ACQUIRE on exit.
        while (__hip_atomic_load(&base[32], __ATOMIC_RELAXED, __HIP_MEMORY_SCOPE_AGENT) < ep)
            __builtin_amdgcn_s_sleep(2);
        (void)__hip_atomic_load(&base[32], __ATOMIC_ACQUIRE, __HIP_MEMORY_SCOPE_AGENT);
    }
    __syncthreads();
}

// ================= persistent LSTM-only recurrence: 1 per-mg barrier/step ==========
// 128 blocks: jg = bid>>2 (16 h-cols), mg = bid&3 (32 batch rows).
// Block (jg,mg) reads h rows [mg*32, mg*32+32) which are produced exactly by the
// 32 blocks sharing its mg -> barrier partitions into 4 independent 32-block groups.
// WhhT slice + c-state live in LDS for all 20 steps. Attention fully deferred.
__global__ __launch_bounds__(256, 1) void decode_loop(
        const u16* __restrict__ WhhT, const float* __restrict__ Xin,
        const float* __restrict__ c0, u16* __restrict__ Hall,
        int* __restrict__ bar) {

    __shared__ __align__(16) u16 Whs[64 * 512];      // 64 KB: row r = g*16+lr, XOR-swizzled
    __shared__ __align__(16) u16 hstage[32 * 512];   // 32 KB, XOR-swizzled h slice
    __shared__ float gl[4 * 32 * 16];                // 8 KB gates
    __shared__ float csh[32 * 16];                   // 2 KB c-state (resident)

    const int tid = threadIdx.x;
    const int wave = tid >> 6, lane = tid & 63;
    const int lm = lane & 15, q = lane >> 4;
    const int bid = blockIdx.x;
    const int jg = bid >> 2, mg = bid & 3;
    int* mybar = bar + mg * 64;                      // 256-B stride per mg group

    // ---- prologue: stage WhhT slice (64 rows x 512) swizzled; c0 into LDS ----
    #pragma unroll
    for (int i = 0; i < 16; ++i) {
        int row = i * 4 + wave;                      // 0..63, wave-uniform
        int g = row >> 4, lr = row & 15;
        int grow = g * H_ + jg * 16 + lr;            // WhhT row (gate col index)
        load_lds16(WhhT + (size_t)grow * H_ + (size_t)(lane ^ (row & 7)) * 8,
                   (char*)Whs + row * 1024);
    }
    #pragma unroll
    for (int ii = 0; ii < 2; ++ii) {
        int idx = tid + ii * 256;
        int lb = idx >> 4, jj = idx & 15;
        csh[idx] = c0[(size_t)(mg * 32 + lb) * H_ + jg * 16 + jj];
    }

    for (int t = 0; t < T_; ++t) {
        const u16* hprev = Hall + (size_t)t * B_ * H_;
        u16* hnext = Hall + (size_t)(t + 1) * B_ * H_;

        // ---- stage h slice (32 rows), pre-swizzled source ----
        #pragma unroll
        for (int it = 0; it < 8; ++it) {
            int row = it * 4 + wave;                 // 0..31, wave-uniform
            load_lds16(hprev + (size_t)(mg * 32 + row) * H_ + (size_t)(lane ^ (row & 7)) * 8,
                       (char*)hstage + row * 1024);
        }
        __syncthreads();                             // drains global_load_lds (prologue too)

        // ---- gates MFMA: wave g computes its gate's 32x16 tile ----
        floatx4 acc0 = {0.f, 0.f, 0.f, 0.f}, acc1 = {0.f, 0.f, 0.f, 0.f};
        #pragma unroll
        for (int kt = 0; kt < 16; ++kt) {
            int ch = kt * 4 + q;
            short8 a0 = *(const short8*)&hstage[(lm << 9) + ((ch ^ (lm & 7)) << 3)];
            short8 a1 = *(const short8*)&hstage[((16 + lm) << 9) + ((ch ^ (lm & 7)) << 3)];
            short8 bb = *(const short8*)&Whs[((wave * 16 + lm) << 9) + ((ch ^ (lm & 7)) << 3)];
            acc0 = __builtin_amdgcn_mfma_f32_16x16x32_bf16(a0, bb, acc0, 0, 0, 0);
            acc1 = __builtin_amdgcn_mfma_f32_16x16x32_bf16(a1, bb, acc1, 0, 0, 0);
        }
        #pragma unroll
        for (int r = 0; r < 4; ++r) {
            gl[wave * 512 + (q * 4 + r) * 16 + lm] = acc0[r];
            gl[wave * 512 + (16 + q * 4 + r) * 16 + lm] = acc1[r];
        }
        __syncthreads();

        // ---- LSTM elementwise; write h into Hall[t+1] only (Hcat deferred) ----
        #pragma unroll
        for (int ii = 0; ii < 2; ++ii) {
            int idx = tid + ii * 256;
            int lb = idx >> 4, jj = idx & 15;
            int grow = mg * 32 + lb, j = jg * 16 + jj;
            const float* xt = Xin + ((size_t)t * B_ + grow) * (4 * H_);
            float gi = gl[0 * 512 + lb * 16 + jj] + xt[j];
            float gf = gl[1 * 512 + lb * 16 + jj] + xt[H_ + j];
            float gg = gl[2 * 512 + lb * 16 + jj] + xt[2 * H_ + j];
            float go = gl[3 * 512 + lb * 16 + jj] + xt[3 * H_ + j];
            float cn = sigm(gf) * csh[idx] + sigm(gi) * fast_tanh(gg);
            csh[idx] = cn;
            hnext[(size_t)grow * H_ + j] = f2b(sigm(go) * fast_tanh(cn));
        }

        grid_sync_mg(mybar, t + 1);   // publish h(t) within this mg group
    }
}

// ================= deferred attention: per (b, t-half), all data staged in LDS ======
// grid 256: b = bid>>1, t in [th*10, th*10+10). Reads ahbuf (f32) from the batched GEMM.
// Also copies Hcat left half (h) from Hall (moved out of the recurrence loop).
__global__ __launch_bounds__(256) void attn_post(
        const float* __restrict__ ahbuf, const u16* __restrict__ Vprojb,
        const u16* __restrict__ feat, const float* __restrict__ wo,
        const u16* __restrict__ Hall, u16* __restrict__ Hcat) {
    __shared__ __align__(16) u16 Vsh[F_ * H_];   // 49 KB
    __shared__ __align__(16) u16 fsh[F_ * H_];   // 49 KB
    __shared__ float ash[H_];
    __shared__ float wosh[H_];
    __shared__ float sc[64];

    const int tid = threadIdx.x;
    const int wave = tid >> 6, lane = tid & 63;
    const int b = blockIdx.x >> 1, th = blockIdx.x & 1;

    const short8* vsrc = (const short8*)(Vprojb + (size_t)b * F_ * H_);
    const short8* fsrc = (const short8*)(feat + (size_t)b * F_ * H_);
    for (int i = tid; i < F_ * H_ / 8; i += 256) {
        ((short8*)Vsh)[i] = vsrc[i];
        ((short8*)fsh)[i] = fsrc[i];
    }
    for (int i = tid; i < H_; i += 256) wosh[i] = wo[i];
    __syncthreads();

    for (int t = th * (T_ / 2); t < (th + 1) * (T_ / 2); ++t) {
        for (int i = tid; i < H_; i += 256)
            ash[i] = ahbuf[((size_t)t * B_ + b) * H_ + i];
        __syncthreads();

        // scores[f] = sum_h wo[h] * tanh(Vproj[b,f,h] + ah[h])
        for (int f = wave; f < F_; f += 4) {
            short8 vv = *(const short8*)&Vsh[f * H_ + lane * 8];
            float s = 0.f;
            #pragma unroll
            for (int e = 0; e < 8; ++e) {
                int h = lane * 8 + e;
                s += wosh[h] * fast_tanh(b2f((u16)vv[e]) + ash[h]);
            }
            #pragma unroll
            for (int off = 32; off; off >>= 1) s += __shfl_xor(s, off);
            if (lane == 0) sc[f] = s;
        }
        __syncthreads();

        if (tid < 64) {
            float v = (tid < F_) ? sc[tid] : -1e30f;
            float m = v;
            #pragma unroll
            for (int off = 32; off; off >>= 1) m = fmaxf(m, __shfl_xor(m, off));
            float e = (tid < F_) ? __expf(v - m) : 0.f;
            float sum = e;
            #pragma unroll
            for (int off = 32; off; off >>= 1) sum += __shfl_xor(sum, off);
            if (tid < F_) sc[tid] = e / sum;
        }
        __syncthreads();

        const size_t rowo = ((size_t)b * T_ + t) * (2 * H_);
        // Hcat left half: copy h(t+1) row b from Hall (vectorized)
        const short8* hrow = (const short8*)(Hall + ((size_t)(t + 1) * B_ + b) * H_);
        for (int i = tid; i < H_ / 8; i += 256)
            ((short8*)(Hcat + rowo))[i] = hrow[i];
        // Hcat right half: attended
        for (int h = tid; h < H_; h += 256) {
            float acc = 0.f;
            #pragma unroll
            for (int f = 0; f < F_; ++f) acc += b2f(fsh[f * H_ + h]) * sc[f];
            Hcat[rowo + H_ + h] = f2b(acc);
        }
        __syncthreads();   // sc/ash reused next t
    }
}

// ========== m97-style bf16 MFMA GEMM: C[M,N] = A[M,K] @ Bt[N,K]^T (+bias) ==========
template <int WRITE_BF16>
__global__ __launch_bounds__(256) void gemm2(const u16* __restrict__ A, int lda,
                                             const u16* __restrict__ Bt, int ldb,
                                             void* __restrict__ Cout, int ldc,
                                             const float* __restrict__ bias1,
                                             const float* __restrict__ bias2,
                                             int M, int N, int K) {
    __shared__ __align__(16) u16 As[128 * 32];
    __shared__ __align__(16) u16 Bs[128 * 32];
    const int tid = threadIdx.x, wave = tid >> 6, lane = tid & 63;
    const int wr = wave >> 1, wc = wave & 1;
    const int lm = lane & 15, q = lane >> 4;
    const int m0 = blockIdx.x * 128, n0 = blockIdx.y * 128;

    const int off = wave * 1024 + lane * 16;
    const int r0 = off >> 6;
    const int c0 = (off & 63) >> 1;

    const u16* gA0 = A + (size_t)(m0 + r0) * lda + c0;
    const u16* gA1 = A + (size_t)(m0 + r0 + 64) * lda + c0;
    int nb0 = n0 + r0;      if (nb0 > N - 1) nb0 = N - 1;
    int nb1 = n0 + r0 + 64; if (nb1 > N - 1) nb1 = N - 1;
    const u16* gB0 = Bt + (size_t)nb0 * ldb + c0;
    const u16* gB1 = Bt + (size_t)nb1 * ldb + c0;
    char* lA0 = (char*)As + wave * 1024;
    char* lA1 = (char*)As + 4096 + wave * 1024;
    char* lB0 = (char*)Bs + wave * 1024;
    char* lB1 = (char*)Bs + 4096 + wave * 1024;

    floatx4 acc[4][4];
    #pragma unroll
    for (int i = 0; i < 4; ++i)
        #pragma unroll
        for (int j = 0; j < 4; ++j) acc[i][j] = floatx4{0.f, 0.f, 0.f, 0.f};

    const int nkt = K >> 5;
    for (int kt = 0; kt < nkt; ++kt) {
        const int ko = kt * 32;
        load_lds16(gA0 + ko, lA0);
        load_lds16(gA1 + ko, lA1);
        load_lds16(gB0 + ko, lB0);
        load_lds16(gB1 + ko, lB1);
        __syncthreads();
        short8 af[4], bf[4];
        #pragma unroll
        for (int i = 0; i < 4; ++i)
            af[i] = *(const short8*)&As[(wr * 64 + i * 16 + lm) * 32 + q * 8];
        #pragma unroll
        for (int j = 0; j < 4; ++j)
            bf[j] = *(const short8*)&Bs[(wc * 64 + j * 16 + lm) * 32 + q * 8];
        #pragma unroll
        for (int i = 0; i < 4; ++i)
            #pragma unroll
            for (int j = 0; j < 4; ++j)
                acc[i][j] = __builtin_amdgcn_mfma_f32_16x16x32_bf16(af[i], bf[j], acc[i][j], 0, 0, 0);
        __syncthreads();
    }

    #pragma unroll
    for (int i = 0; i < 4; ++i) {
        const int row = m0 + wr * 64 + i * 16 + q * 4;
        #pragma unroll
        for (int j = 0; j < 4; ++j) {
            const int col = n0 + wc * 64 + j * 16 + lm;
            if (col < N) {
                #pragma unroll
                for (int r = 0; r < 4; ++r) {
                    float v = acc[i][j][r];
                    if (bias1) v += bias1[col];
                    if (bias2) v += bias2[col];
                    if (WRITE_BF16) ((u16*)Cout)[(size_t)(row + r) * ldc + col] = f2b(v);
                    else            ((float*)Cout)[(size_t)(row + r) * ldc + col] = v;
                }
            }
        }
    }
}

extern "C" void kernel_launch(void* const* d_in, const int* in_sizes, int n_in,
                              void* d_out, int out_size, void* d_ws, size_t ws_size,
                              hipStream_t stream) {
    const int*   cap   = (const int*)d_in[0];
    const float* gf    = (const float*)d_in[1];
    const float* area  = (const float*)d_in[2];
    const float* h0    = (const float*)d_in[3];
    const float* c0    = (const float*)d_in[4];
    const float* emb   = (const float*)d_in[5];
    const float* W_ih  = (const float*)d_in[6];
    const float* W_hh  = (const float*)d_in[7];
    const float* b_ih  = (const float*)d_in[8];
    const float* b_hh  = (const float*)d_in[9];
    const float* Wv    = (const float*)d_in[10];
    const float* Wh    = (const float*)d_in[11];
    const float* wo    = (const float*)d_in[12];
    const float* W_out = (const float*)d_in[13];
    const float* b_out = (const float*)d_in[14];
    float* out = (float*)d_out;

    char* p = (char*)d_ws;
    auto alloc = [&](size_t bytes) {
        char* q = p;
        p += (bytes + 255) & ~(size_t)255;
        return q;
    };
    u16*   X      = (u16*)alloc((size_t)T_ * B_ * 2 * H_ * 2);     // [2560,1024]
    u16*   WihT   = (u16*)alloc((size_t)4 * H_ * 2 * H_ * 2);      // [2048,1024]
    u16*   WhhT   = (u16*)alloc((size_t)4 * H_ * H_ * 2);          // [2048,512]
    u16*   WvT    = (u16*)alloc((size_t)H_ * H_ * 2);              // [512,512]
    u16*   WhT    = (u16*)alloc((size_t)H_ * H_ * 2);              // [512,512]
    u16*   WoutT  = (u16*)alloc((size_t)V_ * 2 * H_ * 2);          // [10000,1024]
    u16*   feat   = (u16*)alloc((size_t)B_ * F_ * H_ * 2);         // [6272,512]
    float* Xin    = (float*)alloc((size_t)T_ * B_ * 4 * H_ * 4);   // [2560,2048] f32
    u16*   Vprojb = (u16*)alloc((size_t)B_ * F_ * H_ * 2);         // [6272,512] bf16
    float* ahbuf  = (float*)alloc((size_t)T_ * B_ * H_ * 4);       // [2560,512] f32
    u16*   Hall   = (u16*)alloc((size_t)(T_ + 1) * B_ * H_ * 2);   // [21,128,512]
    int*   bar    = (int*)alloc(1024);
    u16*   Hcat   = (u16*)alloc((size_t)B_ * T_ * 2 * H_ * 2);     // [2560,1024]

    dim3 tb(32, 8);
    transpose_cvt<<<dim3(4 * H_ / 32, 2 * H_ / 32), tb, 0, stream>>>(W_ih, WihT, 2 * H_, 4 * H_);
    transpose_cvt<<<dim3(4 * H_ / 32, H_ / 32), tb, 0, stream>>>(W_hh, WhhT, H_, 4 * H_);
    transpose_cvt<<<dim3(H_ / 32, H_ / 32), tb, 0, stream>>>(Wv, WvT, H_, H_);
    transpose_cvt<<<dim3(H_ / 32, H_ / 32), tb, 0, stream>>>(Wh, WhT, H_, H_);
    transpose_cvt<<<dim3((V_ + 31) / 32, 2 * H_ / 32), tb, 0, stream>>>(W_out, WoutT, 2 * H_, V_);
    build_x<<<T_ * B_, 256, 0, stream>>>(cap, emb, gf, X);
    feat_cvt<<<(B_ * F_ * H_ + 255) / 256, 256, 0, stream>>>(area, feat);
    init_hc<<<(B_ * H_ + 255) / 256, 256, 0, stream>>>(h0, Hall, bar);

    // Xin = X @ W_ih + b_ih + b_hh   [2560,2048] f32
    gemm2<0><<<dim3(T_ * B_ / 128, 4 * H_ / 128), 256, 0, stream>>>(
        X, 2 * H_, WihT, 2 * H_, Xin, 4 * H_, b_ih, b_hh, T_ * B_, 4 * H_, 2 * H_);
    // Vproj = feat @ Wv  -> bf16 [6272,512]
    gemm2<1><<<dim3(B_ * F_ / 128, H_ / 128), 256, 0, stream>>>(
        feat, H_, WvT, H_, Vprojb, H_, nullptr, nullptr, B_ * F_, H_, H_);

    // LSTM-only persistent recurrence (attention deferred; per-mg barriers)
    decode_loop<<<NBLK_, 256, 0, stream>>>(WhhT, Xin, c0, Hall, bar);

    // ah_all = Hall[1..T] @ Wh   [2560,512] f32 (batched over all t)
    gemm2<0><<<dim3(T_ * B_ / 128, H_ / 128), 256, 0, stream>>>(
        Hall + (size_t)B_ * H_, H_, WhT, H_, ahbuf, H_, nullptr, nullptr, T_ * B_, H_, H_);

    // scores/softmax/attended for all (b,t) in parallel (+ Hcat left-half copy)
    attn_post<<<2 * B_, 256, 0, stream>>>(ahbuf, Vprojb, feat, wo, Hall, Hcat);

    // out = Hcat @ W_out + b_out   [2560,10000] f32
    gemm2<0><<<dim3(T_ * B_ / 128, (V_ + 127) / 128), 256, 0, stream>>>(
        Hcat, 2 * H_, WoutT, 2 * H_, out, V_, b_out, nullptr, T_ * B_, V_, 2 * H_);
}

// Round 5
// 601.317 us; speedup vs baseline: 2.9732x; 1.0852x over previous
//
#include <hip/hip_runtime.h>

#define B_ 128
#define T_ 20
#define V_ 10000
#define H_ 512
#define F_ 49
#define NBLK_ 128

typedef unsigned short u16;
typedef __attribute__((ext_vector_type(8))) short short8;
typedef __attribute__((ext_vector_type(4))) float floatx4;

#define GLOBAL_AS __attribute__((address_space(1)))
#define LDS_AS    __attribute__((address_space(3)))

__device__ inline void load_lds16(const void* g, void* l) {
    __builtin_amdgcn_global_load_lds((const GLOBAL_AS void*)g, (LDS_AS void*)l, 16, 0, 0);
}

// fp32 -> bf16 round-to-nearest-even
__device__ inline u16 f2b(float v) {
    unsigned u = __builtin_bit_cast(unsigned, v);
    unsigned rounding = 0x7FFFu + ((u >> 16) & 1u);
    return (u16)((u + rounding) >> 16);
}
__device__ inline float b2f(u16 h) {
    unsigned u = ((unsigned)h) << 16;
    return __builtin_bit_cast(float, u);
}
__device__ inline float fast_tanh(float x) {
    return 1.f - 2.f / (__expf(2.f * x) + 1.f);
}
__device__ inline float sigm(float x) { return 1.f / (1.f + __expf(-x)); }

// ---------------- 32x32 transpose+cvt tile (device fn; block-uniform call) ----------
__device__ __forceinline__ void tr32(const float* __restrict__ src, u16* __restrict__ dst,
                                     int K, int N, int bx, int by, int tx, int ty,
                                     float (*tile)[33]) {
    int n0 = bx * 32, k0 = by * 32;
    #pragma unroll
    for (int i = 0; i < 32; i += 8) {
        int k = k0 + ty + i, n = n0 + tx;
        tile[ty + i][tx] = (k < K && n < N) ? src[(size_t)k * N + n] : 0.f;
    }
    __syncthreads();
    #pragma unroll
    for (int i = 0; i < 32; i += 8) {
        int n = n0 + ty + i, k = k0 + tx;
        if (n < N && k < K) dst[(size_t)n * K + k] = f2b(tile[tx][ty + i]);
    }
}

// ================= fused preamble: all transposes + build_x + feat_cvt + init =======
// Block ranges:
//  [0,2048)      W_ih^T   (K=1024,N=2048, 64x32 tiles)
//  [2048,3072)   W_hh^T   (K=512, N=2048, 64x16)
//  [3072,3328)   Wv^T     (K=512, N=512, 16x16)
//  [3328,3584)   Wh^T     (16x16)
//  [3584,13600)  W_out^T  (K=1024,N=10000, 313x32)
//  [13600,16160) build_x  (2560 rows)
//  [16160,19296) feat_cvt (3136 blocks x 1024 elems)
//  [19296,19552) init Hall[0]/bar (256 blocks)
__global__ __launch_bounds__(256) void preamble(
        const float* __restrict__ W_ih, const float* __restrict__ W_hh,
        const float* __restrict__ Wv, const float* __restrict__ Wh,
        const float* __restrict__ W_out, const int* __restrict__ cap,
        const float* __restrict__ emb, const float* __restrict__ gf,
        const float* __restrict__ area, const float* __restrict__ h0,
        u16* __restrict__ WihT, u16* __restrict__ WhhT, u16* __restrict__ WvT,
        u16* __restrict__ WhT, u16* __restrict__ WoutT, u16* __restrict__ X,
        u16* __restrict__ feat, u16* __restrict__ Hall, int* __restrict__ bar) {
    __shared__ float tile[32][33];
    const int bid = blockIdx.x, tid = threadIdx.x;
    const int tx = tid & 31, ty = tid >> 5;

    if (bid < 2048) {
        int r = bid;                 tr32(W_ih, WihT, 1024, 2048, r % 64, r / 64, tx, ty, tile);
    } else if (bid < 3072) {
        int r = bid - 2048;          tr32(W_hh, WhhT, 512, 2048, r % 64, r / 64, tx, ty, tile);
    } else if (bid < 3328) {
        int r = bid - 3072;          tr32(Wv, WvT, 512, 512, r % 16, r / 16, tx, ty, tile);
    } else if (bid < 3584) {
        int r = bid - 3328;          tr32(Wh, WhT, 512, 512, r % 16, r / 16, tx, ty, tile);
    } else if (bid < 13600) {
        int r = bid - 3584;          tr32(W_out, WoutT, 1024, 10000, r % 313, r / 313, tx, ty, tile);
    } else if (bid < 16160) {
        int r = bid - 13600;         // r = t*128 + b
        int t = r / B_, b = r % B_;
        int tok = cap[b * T_ + t];
        for (int col = tid; col < 2 * H_; col += 256) {
            float v = (col < H_) ? emb[(size_t)tok * H_ + col] : gf[(size_t)b * H_ + (col - H_)];
            X[(size_t)r * (2 * H_) + col] = f2b(v);
        }
    } else if (bid < 19296) {
        int r = bid - 16160;
        #pragma unroll
        for (int k = 0; k < 4; ++k) {
            int idx = r * 1024 + k * 256 + tid;   // < 128*49*512 = 3211264 by construction
            int h = idx & (H_ - 1);
            int bf_ = idx >> 9;
            int f = bf_ % F_, b = bf_ / F_;
            feat[idx] = f2b(area[((size_t)b * H_ + h) * F_ + f]);
        }
    } else {
        int r = bid - 19296;
        int i = r * 256 + tid;                    // covers B_*H_ = 65536
        Hall[i] = f2b(h0[i]);
        if (r == 0) bar[tid] = 0;
    }
}

// ---------------- per-mg grid barrier: 32 blocks, monotonic counter ----------------
__device__ inline void grid_sync_mg(int* base, int ep) {
    __syncthreads();   // drains vmcnt: all h-stores (and prefetch loads) complete
    if (threadIdx.x == 0) {
        int old = __hip_atomic_fetch_add(&base[0], 1, __ATOMIC_ACQ_REL, __HIP_MEMORY_SCOPE_AGENT);
        if (old == ep * 32 - 1)
            __hip_atomic_store(&base[32], ep, __ATOMIC_RELEASE, __HIP_MEMORY_SCOPE_AGENT);
        while (__hip_atomic_load(&base[32], __ATOMIC_RELAXED, __HIP_MEMORY_SCOPE_AGENT) < ep)
            __builtin_amdgcn_s_sleep(2);
        (void)__hip_atomic_load(&base[32], __ATOMIC_ACQUIRE, __HIP_MEMORY_SCOPE_AGENT);
    }
    __syncthreads();
}

// ================= persistent LSTM-only recurrence =================================
// 128 blocks: jg = bid>>2 (16 h-cols), mg = bid&3 (32 batch rows). 4 x 32-block
// barrier groups. WhhT slice + c-state LDS-resident. Xin prefetched into regs a
// step ahead (hides cold-read latency under the barrier wait). No final barrier
// (kernel boundary orders the last h publish).
__global__ __launch_bounds__(256, 1) void decode_loop(
        const u16* __restrict__ WhhT, const float* __restrict__ Xin,
        const float* __restrict__ c0, u16* __restrict__ Hall,
        int* __restrict__ bar) {

    __shared__ __align__(16) u16 Whs[64 * 512];      // 64 KB, XOR-swizzled
    __shared__ __align__(16) u16 hstage[32 * 512];   // 32 KB, XOR-swizzled
    __shared__ float gl[4 * 32 * 16];                // 8 KB gates
    __shared__ float csh[32 * 16];                   // 2 KB c-state (resident)

    const int tid = threadIdx.x;
    const int wave = tid >> 6, lane = tid & 63;
    const int lm = lane & 15, q = lane >> 4;
    const int bid = blockIdx.x;
    const int jg = bid >> 2, mg = bid & 3;
    int* mybar = bar + mg * 64;

    // fixed per-thread LSTM element coordinates (ii=0: idx=tid, ii=1: idx=tid+256)
    const int lb0 = tid >> 4, jj = tid & 15;
    const int lb1 = lb0 + 16;
    const int grow0 = mg * 32 + lb0, grow1 = mg * 32 + lb1;
    const int j = jg * 16 + jj;

    // ---- prologue: stage WhhT slice swizzled; c0 into LDS ----
    #pragma unroll
    for (int i = 0; i < 16; ++i) {
        int row = i * 4 + wave;                      // 0..63, wave-uniform
        int g = row >> 4, lr = row & 15;
        int grr = g * H_ + jg * 16 + lr;
        load_lds16(WhhT + (size_t)grr * H_ + (size_t)(lane ^ (row & 7)) * 8,
                   (char*)Whs + row * 1024);
    }
    csh[tid] = c0[(size_t)grow0 * H_ + j];
    csh[tid + 256] = c0[(size_t)grow1 * H_ + j];

    // prefetch Xin for t=0
    float xf[8];
    {
        const float* x0 = Xin + (size_t)grow0 * (4 * H_);
        const float* x1 = Xin + (size_t)grow1 * (4 * H_);
        xf[0] = x0[j]; xf[1] = x0[H_ + j]; xf[2] = x0[2 * H_ + j]; xf[3] = x0[3 * H_ + j];
        xf[4] = x1[j]; xf[5] = x1[H_ + j]; xf[6] = x1[2 * H_ + j]; xf[7] = x1[3 * H_ + j];
    }

    for (int t = 0; t < T_; ++t) {
        const u16* hprev = Hall + (size_t)t * B_ * H_;
        u16* hnext = Hall + (size_t)(t + 1) * B_ * H_;

        // ---- stage h slice (32 rows), pre-swizzled source ----
        #pragma unroll
        for (int it = 0; it < 8; ++it) {
            int row = it * 4 + wave;
            load_lds16(hprev + (size_t)(mg * 32 + row) * H_ + (size_t)(lane ^ (row & 7)) * 8,
                       (char*)hstage + row * 1024);
        }
        __syncthreads();

        // ---- gates MFMA: wave g computes its gate's 32x16 tile ----
        floatx4 acc0 = {0.f, 0.f, 0.f, 0.f}, acc1 = {0.f, 0.f, 0.f, 0.f};
        #pragma unroll
        for (int kt = 0; kt < 16; ++kt) {
            int ch = kt * 4 + q;
            short8 a0 = *(const short8*)&hstage[(lm << 9) + ((ch ^ (lm & 7)) << 3)];
            short8 a1 = *(const short8*)&hstage[((16 + lm) << 9) + ((ch ^ (lm & 7)) << 3)];
            short8 bb = *(const short8*)&Whs[((wave * 16 + lm) << 9) + ((ch ^ (lm & 7)) << 3)];
            acc0 = __builtin_amdgcn_mfma_f32_16x16x32_bf16(a0, bb, acc0, 0, 0, 0);
            acc1 = __builtin_amdgcn_mfma_f32_16x16x32_bf16(a1, bb, acc1, 0, 0, 0);
        }
        #pragma unroll
        for (int r = 0; r < 4; ++r) {
            gl[wave * 512 + (q * 4 + r) * 16 + lm] = acc0[r];
            gl[wave * 512 + (16 + q * 4 + r) * 16 + lm] = acc1[r];
        }
        __syncthreads();

        // ---- consume current xf, then issue prefetch for t+1 (overlaps LSTM+barrier)
        float xc[8];
        #pragma unroll
        for (int i = 0; i < 8; ++i) xc[i] = xf[i];
        if (t + 1 < T_) {
            const float* x0 = Xin + ((size_t)(t + 1) * B_ + grow0) * (4 * H_);
            const float* x1 = Xin + ((size_t)(t + 1) * B_ + grow1) * (4 * H_);
            xf[0] = x0[j]; xf[1] = x0[H_ + j]; xf[2] = x0[2 * H_ + j]; xf[3] = x0[3 * H_ + j];
            xf[4] = x1[j]; xf[5] = x1[H_ + j]; xf[6] = x1[2 * H_ + j]; xf[7] = x1[3 * H_ + j];
        }

        // ---- LSTM elementwise; write h into Hall[t+1] ----
        {
            float gi = gl[0 * 512 + lb0 * 16 + jj] + xc[0];
            float gf = gl[1 * 512 + lb0 * 16 + jj] + xc[1];
            float gg = gl[2 * 512 + lb0 * 16 + jj] + xc[2];
            float go = gl[3 * 512 + lb0 * 16 + jj] + xc[3];
            float cn = sigm(gf) * csh[tid] + sigm(gi) * fast_tanh(gg);
            csh[tid] = cn;
            hnext[(size_t)grow0 * H_ + j] = f2b(sigm(go) * fast_tanh(cn));
        }
        {
            float gi = gl[0 * 512 + lb1 * 16 + jj] + xc[4];
            float gf = gl[1 * 512 + lb1 * 16 + jj] + xc[5];
            float gg = gl[2 * 512 + lb1 * 16 + jj] + xc[6];
            float go = gl[3 * 512 + lb1 * 16 + jj] + xc[7];
            float cn = sigm(gf) * csh[tid + 256] + sigm(gi) * fast_tanh(gg);
            csh[tid + 256] = cn;
            hnext[(size_t)grow1 * H_ + j] = f2b(sigm(go) * fast_tanh(cn));
        }

        if (t + 1 < T_) grid_sync_mg(mybar, t + 1);   // publish h(t) within mg group
    }
}

// ================= deferred attention: per (b, t-half), all data staged in LDS ======
__global__ __launch_bounds__(256) void attn_post(
        const float* __restrict__ ahbuf, const u16* __restrict__ Vprojb,
        const u16* __restrict__ feat, const float* __restrict__ wo,
        const u16* __restrict__ Hall, u16* __restrict__ Hcat) {
    __shared__ __align__(16) u16 Vsh[F_ * H_];   // 49 KB
    __shared__ __align__(16) u16 fsh[F_ * H_];   // 49 KB
    __shared__ float ash[H_];
    __shared__ float wosh[H_];
    __shared__ float sc[64];

    const int tid = threadIdx.x;
    const int wave = tid >> 6, lane = tid & 63;
    const int b = blockIdx.x >> 1, th = blockIdx.x & 1;

    const short8* vsrc = (const short8*)(Vprojb + (size_t)b * F_ * H_);
    const short8* fsrc = (const short8*)(feat + (size_t)b * F_ * H_);
    for (int i = tid; i < F_ * H_ / 8; i += 256) {
        ((short8*)Vsh)[i] = vsrc[i];
        ((short8*)fsh)[i] = fsrc[i];
    }
    for (int i = tid; i < H_; i += 256) wosh[i] = wo[i];
    __syncthreads();

    for (int t = th * (T_ / 2); t < (th + 1) * (T_ / 2); ++t) {
        for (int i = tid; i < H_; i += 256)
            ash[i] = ahbuf[((size_t)t * B_ + b) * H_ + i];
        __syncthreads();

        for (int f = wave; f < F_; f += 4) {
            short8 vv = *(const short8*)&Vsh[f * H_ + lane * 8];
            float s = 0.f;
            #pragma unroll
            for (int e = 0; e < 8; ++e) {
                int h = lane * 8 + e;
                s += wosh[h] * fast_tanh(b2f((u16)vv[e]) + ash[h]);
            }
            #pragma unroll
            for (int off = 32; off; off >>= 1) s += __shfl_xor(s, off);
            if (lane == 0) sc[f] = s;
        }
        __syncthreads();

        if (tid < 64) {
            float v = (tid < F_) ? sc[tid] : -1e30f;
            float m = v;
            #pragma unroll
            for (int off = 32; off; off >>= 1) m = fmaxf(m, __shfl_xor(m, off));
            float e = (tid < F_) ? __expf(v - m) : 0.f;
            float sum = e;
            #pragma unroll
            for (int off = 32; off; off >>= 1) sum += __shfl_xor(sum, off);
            if (tid < F_) sc[tid] = e / sum;
        }
        __syncthreads();

        const size_t rowo = ((size_t)b * T_ + t) * (2 * H_);
        const short8* hrow = (const short8*)(Hall + ((size_t)(t + 1) * B_ + b) * H_);
        for (int i = tid; i < H_ / 8; i += 256)
            ((short8*)(Hcat + rowo))[i] = hrow[i];
        for (int h = tid; h < H_; h += 256) {
            float acc = 0.f;
            #pragma unroll
            for (int f = 0; f < F_; ++f) acc += b2f(fsh[f * H_ + h]) * sc[f];
            Hcat[rowo + H_ + h] = f2b(acc);
        }
        __syncthreads();
    }
}

// ========== m97-style bf16 MFMA GEMM body: C[M,N] = A[M,K] @ Bt[N,K]^T (+bias) ======
template <int WRITE_BF16>
__device__ __forceinline__ void gemm2_body(
        const u16* __restrict__ A, int lda, const u16* __restrict__ Bt, int ldb,
        void* __restrict__ Cout, int ldc, const float* __restrict__ bias1,
        const float* __restrict__ bias2, int M, int N, int K, int bx, int by,
        u16* As, u16* Bs) {
    const int tid = threadIdx.x, wave = tid >> 6, lane = tid & 63;
    const int wr = wave >> 1, wc = wave & 1;
    const int lm = lane & 15, q = lane >> 4;
    const int m0 = bx * 128, n0 = by * 128;

    const int off = wave * 1024 + lane * 16;
    const int r0 = off >> 6;
    const int c0 = (off & 63) >> 1;

    const u16* gA0 = A + (size_t)(m0 + r0) * lda + c0;
    const u16* gA1 = A + (size_t)(m0 + r0 + 64) * lda + c0;
    int nb0 = n0 + r0;      if (nb0 > N - 1) nb0 = N - 1;
    int nb1 = n0 + r0 + 64; if (nb1 > N - 1) nb1 = N - 1;
    const u16* gB0 = Bt + (size_t)nb0 * ldb + c0;
    const u16* gB1 = Bt + (size_t)nb1 * ldb + c0;
    char* lA0 = (char*)As + wave * 1024;
    char* lA1 = (char*)As + 4096 + wave * 1024;
    char* lB0 = (char*)Bs + wave * 1024;
    char* lB1 = (char*)Bs + 4096 + wave * 1024;

    floatx4 acc[4][4];
    #pragma unroll
    for (int i = 0; i < 4; ++i)
        #pragma unroll
        for (int jq = 0; jq < 4; ++jq) acc[i][jq] = floatx4{0.f, 0.f, 0.f, 0.f};

    const int nkt = K >> 5;
    for (int kt = 0; kt < nkt; ++kt) {
        const int ko = kt * 32;
        load_lds16(gA0 + ko, lA0);
        load_lds16(gA1 + ko, lA1);
        load_lds16(gB0 + ko, lB0);
        load_lds16(gB1 + ko, lB1);
        __syncthreads();
        short8 af[4], bf[4];
        #pragma unroll
        for (int i = 0; i < 4; ++i)
            af[i] = *(const short8*)&As[(wr * 64 + i * 16 + lm) * 32 + q * 8];
        #pragma unroll
        for (int jq = 0; jq < 4; ++jq)
            bf[jq] = *(const short8*)&Bs[(wc * 64 + jq * 16 + lm) * 32 + q * 8];
        #pragma unroll
        for (int i = 0; i < 4; ++i)
            #pragma unroll
            for (int jq = 0; jq < 4; ++jq)
                acc[i][jq] = __builtin_amdgcn_mfma_f32_16x16x32_bf16(af[i], bf[jq], acc[i][jq], 0, 0, 0);
        __syncthreads();
    }

    #pragma unroll
    for (int i = 0; i < 4; ++i) {
        const int row = m0 + wr * 64 + i * 16 + q * 4;
        #pragma unroll
        for (int jq = 0; jq < 4; ++jq) {
            const int col = n0 + wc * 64 + jq * 16 + lm;
            if (col < N) {
                #pragma unroll
                for (int r = 0; r < 4; ++r) {
                    float v = acc[i][jq][r];
                    if (bias1) v += bias1[col];
                    if (bias2) v += bias2[col];
                    if (WRITE_BF16) ((u16*)Cout)[(size_t)(row + r) * ldc + col] = f2b(v);
                    else            ((float*)Cout)[(size_t)(row + r) * ldc + col] = v;
                }
            }
        }
    }
}

template <int WRITE_BF16>
__global__ __launch_bounds__(256) void gemm2(const u16* __restrict__ A, int lda,
                                             const u16* __restrict__ Bt, int ldb,
                                             void* __restrict__ Cout, int ldc,
                                             const float* __restrict__ bias1,
                                             const float* __restrict__ bias2,
                                             int M, int N, int K) {
    __shared__ __align__(16) u16 As[128 * 32];
    __shared__ __align__(16) u16 Bs[128 * 32];
    gemm2_body<WRITE_BF16>(A, lda, Bt, ldb, Cout, ldc, bias1, bias2, M, N, K,
                           blockIdx.x, blockIdx.y, As, Bs);
}

// ---- grouped: Xin = X@W_ih + biases (320 blocks) ; Vproj = feat@Wv (196 blocks) ----
__global__ __launch_bounds__(256) void gemm_pair(
        const u16* __restrict__ X, const u16* __restrict__ WihT,
        float* __restrict__ Xin, const float* __restrict__ b_ih,
        const float* __restrict__ b_hh, const u16* __restrict__ feat,
        const u16* __restrict__ WvT, u16* __restrict__ Vprojb) {
    __shared__ __align__(16) u16 As[128 * 32];
    __shared__ __align__(16) u16 Bs[128 * 32];
    int bid = blockIdx.x;
    if (bid < 320) {
        gemm2_body<0>(X, 2 * H_, WihT, 2 * H_, Xin, 4 * H_, b_ih, b_hh,
                      T_ * B_, 4 * H_, 2 * H_, bid % 20, bid / 20, As, Bs);
    } else {
        int r = bid - 320;
        gemm2_body<1>(feat, H_, WvT, H_, Vprojb, H_, nullptr, nullptr,
                      B_ * F_, H_, H_, r % 49, r / 49, As, Bs);
    }
}

extern "C" void kernel_launch(void* const* d_in, const int* in_sizes, int n_in,
                              void* d_out, int out_size, void* d_ws, size_t ws_size,
                              hipStream_t stream) {
    const int*   cap   = (const int*)d_in[0];
    const float* gf    = (const float*)d_in[1];
    const float* area  = (const float*)d_in[2];
    const float* h0    = (const float*)d_in[3];
    const float* c0    = (const float*)d_in[4];
    const float* emb   = (const float*)d_in[5];
    const float* W_ih  = (const float*)d_in[6];
    const float* W_hh  = (const float*)d_in[7];
    const float* b_ih  = (const float*)d_in[8];
    const float* b_hh  = (const float*)d_in[9];
    const float* Wv    = (const float*)d_in[10];
    const float* Wh    = (const float*)d_in[11];
    const float* wo    = (const float*)d_in[12];
    const float* W_out = (const float*)d_in[13];
    const float* b_out = (const float*)d_in[14];
    float* out = (float*)d_out;

    char* p = (char*)d_ws;
    auto alloc = [&](size_t bytes) {
        char* q = p;
        p += (bytes + 255) & ~(size_t)255;
        return q;
    };
    u16*   X      = (u16*)alloc((size_t)T_ * B_ * 2 * H_ * 2);     // [2560,1024]
    u16*   WihT   = (u16*)alloc((size_t)4 * H_ * 2 * H_ * 2);      // [2048,1024]
    u16*   WhhT   = (u16*)alloc((size_t)4 * H_ * H_ * 2);          // [2048,512]
    u16*   WvT    = (u16*)alloc((size_t)H_ * H_ * 2);              // [512,512]
    u16*   WhT    = (u16*)alloc((size_t)H_ * H_ * 2);              // [512,512]
    u16*   WoutT  = (u16*)alloc((size_t)V_ * 2 * H_ * 2);          // [10000,1024]
    u16*   feat   = (u16*)alloc((size_t)B_ * F_ * H_ * 2);         // [6272,512]
    float* Xin    = (float*)alloc((size_t)T_ * B_ * 4 * H_ * 4);   // [2560,2048] f32
    u16*   Vprojb = (u16*)alloc((size_t)B_ * F_ * H_ * 2);         // [6272,512] bf16
    float* ahbuf  = (float*)alloc((size_t)T_ * B_ * H_ * 4);       // [2560,512] f32
    u16*   Hall   = (u16*)alloc((size_t)(T_ + 1) * B_ * H_ * 2);   // [21,128,512]
    int*   bar    = (int*)alloc(1024);
    u16*   Hcat   = (u16*)alloc((size_t)B_ * T_ * 2 * H_ * 2);     // [2560,1024]

    // 1) fused preamble (was 8 launches)
    preamble<<<19552, 256, 0, stream>>>(W_ih, W_hh, Wv, Wh, W_out, cap, emb, gf,
                                        area, h0, WihT, WhhT, WvT, WhT, WoutT,
                                        X, feat, Hall, bar);

    // 2) grouped Xin-GEMM + Vproj-GEMM (was 2 launches)
    gemm_pair<<<516, 256, 0, stream>>>(X, WihT, Xin, b_ih, b_hh, feat, WvT, Vprojb);

    // 3) LSTM-only persistent recurrence (attention deferred; per-mg barriers)
    decode_loop<<<NBLK_, 256, 0, stream>>>(WhhT, Xin, c0, Hall, bar);

    // 4) ah_all = Hall[1..T] @ Wh   [2560,512] f32
    gemm2<0><<<dim3(T_ * B_ / 128, H_ / 128), 256, 0, stream>>>(
        Hall + (size_t)B_ * H_, H_, WhT, H_, ahbuf, H_, nullptr, nullptr, T_ * B_, H_, H_);

    // 5) scores/softmax/attended + Hcat assembly
    attn_post<<<2 * B_, 256, 0, stream>>>(ahbuf, Vprojb, feat, wo, Hall, Hcat);

    // 6) out = Hcat @ W_out + b_out   [2560,10000] f32
    gemm2<0><<<dim3(T_ * B_ / 128, (V_ + 127) / 128), 256, 0, stream>>>(
        Hcat, 2 * H_, WoutT, 2 * H_, out, V_, b_out, nullptr, T_ * B_, V_, 2 * H_);
}

// Round 7
// 587.265 us; speedup vs baseline: 3.0443x; 1.0239x over previous
//
#include <hip/hip_runtime.h>

#define B_ 128
#define T_ 20
#define V_ 10000
#define H_ 512
#define F_ 49
#define NBLK_ 128

typedef unsigned short u16;
typedef __attribute__((ext_vector_type(8))) short short8;
typedef __attribute__((ext_vector_type(4))) float floatx4;

#define GLOBAL_AS __attribute__((address_space(1)))
#define LDS_AS    __attribute__((address_space(3)))

__device__ inline void load_lds16(const void* g, void* l) {
    __builtin_amdgcn_global_load_lds((const GLOBAL_AS void*)g, (LDS_AS void*)l, 16, 0, 0);
}

// fp32 -> bf16 round-to-nearest-even
__device__ inline u16 f2b(float v) {
    unsigned u = __builtin_bit_cast(unsigned, v);
    unsigned rounding = 0x7FFFu + ((u >> 16) & 1u);
    return (u16)((u + rounding) >> 16);
}
__device__ inline float b2f(u16 h) {
    unsigned u = ((unsigned)h) << 16;
    return __builtin_bit_cast(float, u);
}
__device__ inline float fast_tanh(float x) {
    return 1.f - 2.f / (__expf(2.f * x) + 1.f);
}
__device__ inline float sigm(float x) { return 1.f / (1.f + __expf(-x)); }

// ---------------- 32x32 transpose+cvt tile (device fn; block-uniform call) ----------
__device__ __forceinline__ void tr32(const float* __restrict__ src, u16* __restrict__ dst,
                                     int K, int N, int bx, int by, int tx, int ty,
                                     float (*tl)[33]) {
    int n0 = bx * 32, k0 = by * 32;
    #pragma unroll
    for (int i = 0; i < 32; i += 8) {
        int k = k0 + ty + i, n = n0 + tx;
        tl[ty + i][tx] = (k < K && n < N) ? src[(size_t)k * N + n] : 0.f;
    }
    __syncthreads();
    #pragma unroll
    for (int i = 0; i < 32; i += 8) {
        int n = n0 + ty + i, k = k0 + tx;
        if (n < N && k < K) dst[(size_t)n * K + k] = f2b(tl[tx][ty + i]);
    }
}

// ================= fused preamble: all transposes + build_x + feat-transpose + init =
// Block ranges:
//  [0,2048)      W_ih^T   (K=1024,N=2048, 64x32 tiles)
//  [2048,3072)   W_hh^T   (K=512, N=2048, 64x16)
//  [3072,3328)   Wv^T     (K=512, N=512, 16x16)
//  [3328,3584)   Wh^T     (16x16)
//  [3584,13600)  W_out^T  (K=1024,N=10000, 313x32)
//  [13600,16160) build_x  (2560 rows)
//  [16160,20256) feat = per-b transpose area[b,H,F] -> [b,F,H] (128 b x 32 tiles)
//  [20256,20512) init Hall[0]/bar (256 blocks)
__global__ __launch_bounds__(256) void preamble(
        const float* __restrict__ W_ih, const float* __restrict__ W_hh,
        const float* __restrict__ Wv, const float* __restrict__ Wh,
        const float* __restrict__ W_out, const int* __restrict__ cap,
        const float* __restrict__ emb, const float* __restrict__ gf,
        const float* __restrict__ area, const float* __restrict__ h0,
        u16* __restrict__ WihT, u16* __restrict__ WhhT, u16* __restrict__ WvT,
        u16* __restrict__ WhT, u16* __restrict__ WoutT, u16* __restrict__ X,
        u16* __restrict__ feat, u16* __restrict__ Hall, int* __restrict__ bar) {
    __shared__ float tl[32][33];
    const int bid = blockIdx.x, tid = threadIdx.x;
    const int tx = tid & 31, ty = tid >> 5;

    if (bid < 2048) {
        int r = bid;                 tr32(W_ih, WihT, 1024, 2048, r % 64, r / 64, tx, ty, tl);
    } else if (bid < 3072) {
        int r = bid - 2048;          tr32(W_hh, WhhT, 512, 2048, r % 64, r / 64, tx, ty, tl);
    } else if (bid < 3328) {
        int r = bid - 3072;          tr32(Wv, WvT, 512, 512, r % 16, r / 16, tx, ty, tl);
    } else if (bid < 3584) {
        int r = bid - 3328;          tr32(Wh, WhT, 512, 512, r % 16, r / 16, tx, ty, tl);
    } else if (bid < 13600) {
        int r = bid - 3584;          tr32(W_out, WoutT, 1024, 10000, r % 313, r / 313, tx, ty, tl);
    } else if (bid < 16160) {
        int r = bid - 13600;         // r = t*128 + b
        int t = r / B_, b = r % B_;
        int tok = cap[b * T_ + t];
        for (int col = tid; col < 2 * H_; col += 256) {
            float v = (col < H_) ? emb[(size_t)tok * H_ + col] : gf[(size_t)b * H_ + (col - H_)];
            X[(size_t)r * (2 * H_) + col] = f2b(v);
        }
    } else if (bid < 20256) {
        // coalesced feat build: per-b 32x32 transpose tiles of area[b][H][F] -> feat[b][F][H]
        int r = bid - 16160;
        int b = r >> 5, t32 = r & 31;
        int fx = t32 & 1, hy = t32 >> 1;          // f-tile (0..1), h-tile (0..15)
        tr32(area + (size_t)b * H_ * F_, feat + (size_t)b * F_ * H_,
             H_, F_, fx, hy, tx, ty, tl);
    } else {
        int r = bid - 20256;
        int i = r * 256 + tid;                    // covers B_*H_ = 65536
        Hall[i] = f2b(h0[i]);
        if (r == 0) bar[tid] = 0;
    }
}

// ---------------- per-mg grid barrier: 32 blocks, monotonic counter ----------------
__device__ inline void grid_sync_mg(int* base, int ep) {
    __syncthreads();   // drains vmcnt: all h-stores (and prefetch loads) complete
    if (threadIdx.x == 0) {
        int old = __hip_atomic_fetch_add(&base[0], 1, __ATOMIC_ACQ_REL, __HIP_MEMORY_SCOPE_AGENT);
        if (old == ep * 32 - 1)
            __hip_atomic_store(&base[32], ep, __ATOMIC_RELEASE, __HIP_MEMORY_SCOPE_AGENT);
        while (__hip_atomic_load(&base[32], __ATOMIC_RELAXED, __HIP_MEMORY_SCOPE_AGENT) < ep)
            __builtin_amdgcn_s_sleep(2);
        (void)__hip_atomic_load(&base[32], __ATOMIC_ACQUIRE, __HIP_MEMORY_SCOPE_AGENT);
    }
    __syncthreads();
}

// ================= persistent LSTM-only recurrence =================================
__global__ __launch_bounds__(256, 1) void decode_loop(
        const u16* __restrict__ WhhT, const float* __restrict__ Xin,
        const float* __restrict__ c0, u16* __restrict__ Hall,
        int* __restrict__ bar) {

    __shared__ __align__(16) u16 Whs[64 * 512];      // 64 KB, XOR-swizzled
    __shared__ __align__(16) u16 hstage[32 * 512];   // 32 KB, XOR-swizzled
    __shared__ float gl[4 * 32 * 16];                // 8 KB gates
    __shared__ float csh[32 * 16];                   // 2 KB c-state (resident)

    const int tid = threadIdx.x;
    const int wave = tid >> 6, lane = tid & 63;
    const int lm = lane & 15, q = lane >> 4;
    const int bid = blockIdx.x;
    const int jg = bid >> 2, mg = bid & 3;
    int* mybar = bar + mg * 64;

    const int lb0 = tid >> 4, jj = tid & 15;
    const int lb1 = lb0 + 16;
    const int grow0 = mg * 32 + lb0, grow1 = mg * 32 + lb1;
    const int j = jg * 16 + jj;

    #pragma unroll
    for (int i = 0; i < 16; ++i) {
        int row = i * 4 + wave;                      // 0..63, wave-uniform
        int g = row >> 4, lr = row & 15;
        int grr = g * H_ + jg * 16 + lr;
        load_lds16(WhhT + (size_t)grr * H_ + (size_t)(lane ^ (row & 7)) * 8,
                   (char*)Whs + row * 1024);
    }
    csh[tid] = c0[(size_t)grow0 * H_ + j];
    csh[tid + 256] = c0[(size_t)grow1 * H_ + j];

    float xf[8];
    {
        const float* x0 = Xin + (size_t)grow0 * (4 * H_);
        const float* x1 = Xin + (size_t)grow1 * (4 * H_);
        xf[0] = x0[j]; xf[1] = x0[H_ + j]; xf[2] = x0[2 * H_ + j]; xf[3] = x0[3 * H_ + j];
        xf[4] = x1[j]; xf[5] = x1[H_ + j]; xf[6] = x1[2 * H_ + j]; xf[7] = x1[3 * H_ + j];
    }

    for (int t = 0; t < T_; ++t) {
        const u16* hprev = Hall + (size_t)t * B_ * H_;
        u16* hnext = Hall + (size_t)(t + 1) * B_ * H_;

        #pragma unroll
        for (int it = 0; it < 8; ++it) {
            int row = it * 4 + wave;
            load_lds16(hprev + (size_t)(mg * 32 + row) * H_ + (size_t)(lane ^ (row & 7)) * 8,
                       (char*)hstage + row * 1024);
        }
        __syncthreads();

        floatx4 acc0 = {0.f, 0.f, 0.f, 0.f}, acc1 = {0.f, 0.f, 0.f, 0.f};
        #pragma unroll
        for (int kt = 0; kt < 16; ++kt) {
            int ch = kt * 4 + q;
            short8 a0 = *(const short8*)&hstage[(lm << 9) + ((ch ^ (lm & 7)) << 3)];
            short8 a1 = *(const short8*)&hstage[((16 + lm) << 9) + ((ch ^ (lm & 7)) << 3)];
            short8 bb = *(const short8*)&Whs[((wave * 16 + lm) << 9) + ((ch ^ (lm & 7)) << 3)];
            acc0 = __builtin_amdgcn_mfma_f32_16x16x32_bf16(a0, bb, acc0, 0, 0, 0);
            acc1 = __builtin_amdgcn_mfma_f32_16x16x32_bf16(a1, bb, acc1, 0, 0, 0);
        }
        #pragma unroll
        for (int r = 0; r < 4; ++r) {
            gl[wave * 512 + (q * 4 + r) * 16 + lm] = acc0[r];
            gl[wave * 512 + (16 + q * 4 + r) * 16 + lm] = acc1[r];
        }
        __syncthreads();

        float xc[8];
        #pragma unroll
        for (int i = 0; i < 8; ++i) xc[i] = xf[i];
        if (t + 1 < T_) {
            const float* x0 = Xin + ((size_t)(t + 1) * B_ + grow0) * (4 * H_);
            const float* x1 = Xin + ((size_t)(t + 1) * B_ + grow1) * (4 * H_);
            xf[0] = x0[j]; xf[1] = x0[H_ + j]; xf[2] = x0[2 * H_ + j]; xf[3] = x0[3 * H_ + j];
            xf[4] = x1[j]; xf[5] = x1[H_ + j]; xf[6] = x1[2 * H_ + j]; xf[7] = x1[3 * H_ + j];
        }

        {
            float gi = gl[0 * 512 + lb0 * 16 + jj] + xc[0];
            float gf = gl[1 * 512 + lb0 * 16 + jj] + xc[1];
            float gg = gl[2 * 512 + lb0 * 16 + jj] + xc[2];
            float go = gl[3 * 512 + lb0 * 16 + jj] + xc[3];
            float cn = sigm(gf) * csh[tid] + sigm(gi) * fast_tanh(gg);
            csh[tid] = cn;
            hnext[(size_t)grow0 * H_ + j] = f2b(sigm(go) * fast_tanh(cn));
        }
        {
            float gi = gl[0 * 512 + lb1 * 16 + jj] + xc[4];
            float gf = gl[1 * 512 + lb1 * 16 + jj] + xc[5];
            float gg = gl[2 * 512 + lb1 * 16 + jj] + xc[6];
            float go = gl[3 * 512 + lb1 * 16 + jj] + xc[7];
            float cn = sigm(gf) * csh[tid + 256] + sigm(gi) * fast_tanh(gg);
            csh[tid + 256] = cn;
            hnext[(size_t)grow1 * H_ + j] = f2b(sigm(go) * fast_tanh(cn));
        }

        if (t + 1 < T_) grid_sync_mg(mybar, t + 1);
    }
}

// ================= deferred attention: per (b, t-half), all data staged in LDS ======
__global__ __launch_bounds__(256) void attn_post(
        const float* __restrict__ ahbuf, const u16* __restrict__ Vprojb,
        const u16* __restrict__ feat, const float* __restrict__ wo,
        const u16* __restrict__ Hall, u16* __restrict__ Hcat) {
    __shared__ __align__(16) u16 Vsh[F_ * H_];   // 49 KB
    __shared__ __align__(16) u16 fsh[F_ * H_];   // 49 KB
    __shared__ float ash[H_];
    __shared__ float wosh[H_];
    __shared__ float sc[64];

    const int tid = threadIdx.x;
    const int wave = tid >> 6, lane = tid & 63;
    const int b = blockIdx.x >> 1, th = blockIdx.x & 1;

    const short8* vsrc = (const short8*)(Vprojb + (size_t)b * F_ * H_);
    const short8* fsrc = (const short8*)(feat + (size_t)b * F_ * H_);
    for (int i = tid; i < F_ * H_ / 8; i += 256) {
        ((short8*)Vsh)[i] = vsrc[i];
        ((short8*)fsh)[i] = fsrc[i];
    }
    for (int i = tid; i < H_; i += 256) wosh[i] = wo[i];
    __syncthreads();

    for (int t = th * (T_ / 2); t < (th + 1) * (T_ / 2); ++t) {
        for (int i = tid; i < H_; i += 256)
            ash[i] = ahbuf[((size_t)t * B_ + b) * H_ + i];
        __syncthreads();

        for (int f = wave; f < F_; f += 4) {
            short8 vv = *(const short8*)&Vsh[f * H_ + lane * 8];
            float s = 0.f;
            #pragma unroll
            for (int e = 0; e < 8; ++e) {
                int h = lane * 8 + e;
                s += wosh[h] * fast_tanh(b2f((u16)vv[e]) + ash[h]);
            }
            #pragma unroll
            for (int off = 32; off; off >>= 1) s += __shfl_xor(s, off);
            if (lane == 0) sc[f] = s;
        }
        __syncthreads();

        if (tid < 64) {
            float v = (tid < F_) ? sc[tid] : -1e30f;
            float m = v;
            #pragma unroll
            for (int off = 32; off; off >>= 1) m = fmaxf(m, __shfl_xor(m, off));
            float e = (tid < F_) ? __expf(v - m) : 0.f;
            float sum = e;
            #pragma unroll
            for (int off = 32; off; off >>= 1) sum += __shfl_xor(sum, off);
            if (tid < F_) sc[tid] = e / sum;
        }
        __syncthreads();

        const size_t rowo = ((size_t)b * T_ + t) * (2 * H_);
        const short8* hrow = (const short8*)(Hall + ((size_t)(t + 1) * B_ + b) * H_);
        for (int i = tid; i < H_ / 8; i += 256)
            ((short8*)(Hcat + rowo))[i] = hrow[i];
        for (int h = tid; h < H_; h += 256) {
            float acc = 0.f;
            #pragma unroll
            for (int f = 0; f < F_; ++f) acc += b2f(fsh[f * H_ + h]) * sc[f];
            Hcat[rowo + H_ + h] = f2b(acc);
        }
        __syncthreads();
    }
}

// ========== 2-phase double-buffered bf16 MFMA GEMM body (T3-minimum) ===============
// C[M,N] = A[M,K] @ Bt[N,K]^T (+bias). One barrier per K-tile; stage k+1 under
// compute of k. As/Bs are 2 x 4096 u16 buffers (32 KB total).
template <int WRITE_BF16>
__device__ __forceinline__ void gemm2_body(
        const u16* __restrict__ A, int lda, const u16* __restrict__ Bt, int ldb,
        void* __restrict__ Cout, int ldc, const float* __restrict__ bias1,
        const float* __restrict__ bias2, int M, int N, int K, int bx, int by,
        u16* As, u16* Bs) {
    const int tid = threadIdx.x, wave = tid >> 6, lane = tid & 63;
    const int wr = wave >> 1, wc = wave & 1;
    const int lm = lane & 15, q = lane >> 4;
    const int m0 = bx * 128, n0 = by * 128;

    const int off = wave * 1024 + lane * 16;
    const int r0 = off >> 6;
    const int c0 = (off & 63) >> 1;

    const u16* gA0 = A + (size_t)(m0 + r0) * lda + c0;
    const u16* gA1 = A + (size_t)(m0 + r0 + 64) * lda + c0;
    int nb0 = n0 + r0;      if (nb0 > N - 1) nb0 = N - 1;
    int nb1 = n0 + r0 + 64; if (nb1 > N - 1) nb1 = N - 1;
    const u16* gB0 = Bt + (size_t)nb0 * ldb + c0;
    const u16* gB1 = Bt + (size_t)nb1 * ldb + c0;

    floatx4 acc[4][4];
    #pragma unroll
    for (int i = 0; i < 4; ++i)
        #pragma unroll
        for (int jq = 0; jq < 4; ++jq) acc[i][jq] = floatx4{0.f, 0.f, 0.f, 0.f};

    const int nkt = K >> 5;
    // prologue: stage tile 0 into buffer 0
    {
        load_lds16(gA0, (char*)As + wave * 1024);
        load_lds16(gA1, (char*)As + 4096 + wave * 1024);
        load_lds16(gB0, (char*)Bs + wave * 1024);
        load_lds16(gB1, (char*)Bs + 4096 + wave * 1024);
    }
    __syncthreads();   // buffer 0 ready

    int cur = 0;
    for (int kt = 0; kt < nkt; ++kt) {
        if (kt + 1 < nkt) {   // stage next tile into the other buffer (overlaps MFMA)
            const int ko = (kt + 1) * 32;
            char* dA = (char*)(As + (cur ^ 1) * 4096);
            char* dB = (char*)(Bs + (cur ^ 1) * 4096);
            load_lds16(gA0 + ko, dA + wave * 1024);
            load_lds16(gA1 + ko, dA + 4096 + wave * 1024);
            load_lds16(gB0 + ko, dB + wave * 1024);
            load_lds16(gB1 + ko, dB + 4096 + wave * 1024);
        }
        const u16* Ab = As + cur * 4096;
        const u16* Bb = Bs + cur * 4096;
        short8 af[4], bf[4];
        #pragma unroll
        for (int i = 0; i < 4; ++i)
            af[i] = *(const short8*)&Ab[(wr * 64 + i * 16 + lm) * 32 + q * 8];
        #pragma unroll
        for (int jq = 0; jq < 4; ++jq)
            bf[jq] = *(const short8*)&Bb[(wc * 64 + jq * 16 + lm) * 32 + q * 8];
        #pragma unroll
        for (int i = 0; i < 4; ++i)
            #pragma unroll
            for (int jq = 0; jq < 4; ++jq)
                acc[i][jq] = __builtin_amdgcn_mfma_f32_16x16x32_bf16(af[i], bf[jq], acc[i][jq], 0, 0, 0);
        __syncthreads();   // drains next-stage vmcnt AND orders buffer reuse
        cur ^= 1;
    }

    #pragma unroll
    for (int i = 0; i < 4; ++i) {
        const int row = m0 + wr * 64 + i * 16 + q * 4;
        #pragma unroll
        for (int jq = 0; jq < 4; ++jq) {
            const int col = n0 + wc * 64 + jq * 16 + lm;
            if (col < N) {
                #pragma unroll
                for (int r = 0; r < 4; ++r) {
                    float v = acc[i][jq][r];
                    if (bias1) v += bias1[col];
                    if (bias2) v += bias2[col];
                    if (WRITE_BF16) ((u16*)Cout)[(size_t)(row + r) * ldc + col] = f2b(v);
                    else            ((float*)Cout)[(size_t)(row + r) * ldc + col] = v;
                }
            }
        }
    }
}

// standalone GEMM with bijective XCD-chunk swizzle (m204) for B-panel L2 locality
template <int WRITE_BF16>
__global__ __launch_bounds__(256) void gemm2(const u16* __restrict__ A, int lda,
                                             const u16* __restrict__ Bt, int ldb,
                                             void* __restrict__ Cout, int ldc,
                                             const float* __restrict__ bias1,
                                             const float* __restrict__ bias2,
                                             int M, int N, int K) {
    __shared__ __align__(16) u16 As[2 * 128 * 32];
    __shared__ __align__(16) u16 Bs[2 * 128 * 32];
    const int nbx = gridDim.x;
    const int nwg = nbx * gridDim.y;
    const int lin = blockIdx.x + blockIdx.y * nbx;
    const int qq = nwg >> 3, rr = nwg & 7;
    const int xcd = lin & 7, idx = lin >> 3;
    const int wg = (xcd < rr ? xcd * (qq + 1) : rr * (qq + 1) + (xcd - rr) * qq) + idx;
    gemm2_body<WRITE_BF16>(A, lda, Bt, ldb, Cout, ldc, bias1, bias2, M, N, K,
                           wg % nbx, wg / nbx, As, Bs);
}

// ---- grouped: Xin = X@W_ih + biases (320 blocks) ; Vproj = feat@Wv (196 blocks) ----
__global__ __launch_bounds__(256) void gemm_pair(
        const u16* __restrict__ X, const u16* __restrict__ WihT,
        float* __restrict__ Xin, const float* __restrict__ b_ih,
        const float* __restrict__ b_hh, const u16* __restrict__ feat,
        const u16* __restrict__ WvT, u16* __restrict__ Vprojb) {
    __shared__ __align__(16) u16 As[2 * 128 * 32];
    __shared__ __align__(16) u16 Bs[2 * 128 * 32];
    int bid = blockIdx.x;
    if (bid < 320) {
        gemm2_body<0>(X, 2 * H_, WihT, 2 * H_, Xin, 4 * H_, b_ih, b_hh,
                      T_ * B_, 4 * H_, 2 * H_, bid % 20, bid / 20, As, Bs);
    } else {
        int r = bid - 320;
        gemm2_body<1>(feat, H_, WvT, H_, Vprojb, H_, nullptr, nullptr,
                      B_ * F_, H_, H_, r % 49, r / 49, As, Bs);
    }
}

extern "C" void kernel_launch(void* const* d_in, const int* in_sizes, int n_in,
                              void* d_out, int out_size, void* d_ws, size_t ws_size,
                              hipStream_t stream) {
    const int*   cap   = (const int*)d_in[0];
    const float* gf    = (const float*)d_in[1];
    const float* area  = (const float*)d_in[2];
    const float* h0    = (const float*)d_in[3];
    const float* c0    = (const float*)d_in[4];
    const float* emb   = (const float*)d_in[5];
    const float* W_ih  = (const float*)d_in[6];
    const float* W_hh  = (const float*)d_in[7];
    const float* b_ih  = (const float*)d_in[8];
    const float* b_hh  = (const float*)d_in[9];
    const float* Wv    = (const float*)d_in[10];
    const float* Wh    = (const float*)d_in[11];
    const float* wo    = (const float*)d_in[12];
    const float* W_out = (const float*)d_in[13];
    const float* b_out = (const float*)d_in[14];
    float* out = (float*)d_out;

    char* p = (char*)d_ws;
    auto alloc = [&](size_t bytes) {
        char* q = p;
        p += (bytes + 255) & ~(size_t)255;
        return q;
    };
    u16*   X      = (u16*)alloc((size_t)T_ * B_ * 2 * H_ * 2);     // [2560,1024]
    u16*   WihT   = (u16*)alloc((size_t)4 * H_ * 2 * H_ * 2);      // [2048,1024]
    u16*   WhhT   = (u16*)alloc((size_t)4 * H_ * H_ * 2);          // [2048,512]
    u16*   WvT    = (u16*)alloc((size_t)H_ * H_ * 2);              // [512,512]
    u16*   WhT    = (u16*)alloc((size_t)H_ * H_ * 2);              // [512,512]
    u16*   WoutT  = (u16*)alloc((size_t)V_ * 2 * H_ * 2);          // [10000,1024]
    u16*   feat   = (u16*)alloc((size_t)B_ * F_ * H_ * 2);         // [6272,512]
    float* Xin    = (float*)alloc((size_t)T_ * B_ * 4 * H_ * 4);   // [2560,2048] f32
    u16*   Vprojb = (u16*)alloc((size_t)B_ * F_ * H_ * 2);         // [6272,512] bf16
    float* ahbuf  = (float*)alloc((size_t)T_ * B_ * H_ * 4);       // [2560,512] f32
    u16*   Hall   = (u16*)alloc((size_t)(T_ + 1) * B_ * H_ * 2);   // [21,128,512]
    int*   bar    = (int*)alloc(1024);
    u16*   Hcat   = (u16*)alloc((size_t)B_ * T_ * 2 * H_ * 2);     // [2560,1024]

    // 1) fused preamble (feat build now coalesced via tiled transpose)
    preamble<<<20512, 256, 0, stream>>>(W_ih, W_hh, Wv, Wh, W_out, cap, emb, gf,
                                        area, h0, WihT, WhhT, WvT, WhT, WoutT,
                                        X, feat, Hall, bar);

    // 2) grouped Xin-GEMM + Vproj-GEMM
    gemm_pair<<<516, 256, 0, stream>>>(X, WihT, Xin, b_ih, b_hh, feat, WvT, Vprojb);

    // 3) LSTM-only persistent recurrence (attention deferred; per-mg barriers)
    decode_loop<<<NBLK_, 256, 0, stream>>>(WhhT, Xin, c0, Hall, bar);

    // 4) ah_all = Hall[1..T] @ Wh   [2560,512] f32
    gemm2<0><<<dim3(T_ * B_ / 128, H_ / 128), 256, 0, stream>>>(
        Hall + (size_t)B_ * H_, H_, WhT, H_, ahbuf, H_, nullptr, nullptr, T_ * B_, H_, H_);

    // 5) scores/softmax/attended + Hcat assembly
    attn_post<<<2 * B_, 256, 0, stream>>>(ahbuf, Vprojb, feat, wo, Hall, Hcat);

    // 6) out = Hcat @ W_out + b_out   [2560,10000] f32
    gemm2<0><<<dim3(T_ * B_ / 128, (V_ + 127) / 128), 256, 0, stream>>>(
        Hcat, 2 * H_, WoutT, 2 * H_, out, V_, b_out, nullptr, T_ * B_, V_, 2 * H_);
}

// Round 8
// 569.154 us; speedup vs baseline: 3.1412x; 1.0318x over previous
//
#include <hip/hip_runtime.h>

#define B_ 128
#define T_ 20
#define V_ 10000
#define H_ 512
#define F_ 49
#define NBLK_ 128

typedef unsigned short u16;
typedef __attribute__((ext_vector_type(8))) short short8;
typedef __attribute__((ext_vector_type(4))) float floatx4;
typedef __attribute__((ext_vector_type(2))) float floatx2;

#define GLOBAL_AS __attribute__((address_space(1)))
#define LDS_AS    __attribute__((address_space(3)))

__device__ inline void load_lds16(const void* g, void* l) {
    __builtin_amdgcn_global_load_lds((const GLOBAL_AS void*)g, (LDS_AS void*)l, 16, 0, 0);
}

// fp32 -> bf16 round-to-nearest-even
__device__ inline u16 f2b(float v) {
    unsigned u = __builtin_bit_cast(unsigned, v);
    unsigned rounding = 0x7FFFu + ((u >> 16) & 1u);
    return (u16)((u + rounding) >> 16);
}
__device__ inline float b2f(u16 h) {
    unsigned u = ((unsigned)h) << 16;
    return __builtin_bit_cast(float, u);
}
__device__ inline float fast_tanh(float x) {
    return 1.f - 2.f / (__expf(2.f * x) + 1.f);
}
__device__ inline float sigm(float x) { return 1.f / (1.f + __expf(-x)); }

// ---------------- 32x32 transpose+cvt tile (device fn; block-uniform call) ----------
__device__ __forceinline__ void tr32(const float* __restrict__ src, u16* __restrict__ dst,
                                     int K, int N, int bx, int by, int tx, int ty,
                                     float (*tl)[33]) {
    int n0 = bx * 32, k0 = by * 32;
    #pragma unroll
    for (int i = 0; i < 32; i += 8) {
        int k = k0 + ty + i, n = n0 + tx;
        tl[ty + i][tx] = (k < K && n < N) ? src[(size_t)k * N + n] : 0.f;
    }
    __syncthreads();
    #pragma unroll
    for (int i = 0; i < 32; i += 8) {
        int n = n0 + ty + i, k = k0 + tx;
        if (n < N && k < K) dst[(size_t)n * K + k] = f2b(tl[tx][ty + i]);
    }
}

// ================= fused preamble: all transposes + build_x + feat-transpose + init =
__global__ __launch_bounds__(256) void preamble(
        const float* __restrict__ W_ih, const float* __restrict__ W_hh,
        const float* __restrict__ Wv, const float* __restrict__ Wh,
        const float* __restrict__ W_out, const int* __restrict__ cap,
        const float* __restrict__ emb, const float* __restrict__ gf,
        const float* __restrict__ area, const float* __restrict__ h0,
        u16* __restrict__ WihT, u16* __restrict__ WhhT, u16* __restrict__ WvT,
        u16* __restrict__ WhT, u16* __restrict__ WoutT, u16* __restrict__ X,
        u16* __restrict__ feat, u16* __restrict__ Hall, int* __restrict__ bar) {
    __shared__ float tl[32][33];
    const int bid = blockIdx.x, tid = threadIdx.x;
    const int tx = tid & 31, ty = tid >> 5;

    if (bid < 2048) {
        int r = bid;                 tr32(W_ih, WihT, 1024, 2048, r % 64, r / 64, tx, ty, tl);
    } else if (bid < 3072) {
        int r = bid - 2048;          tr32(W_hh, WhhT, 512, 2048, r % 64, r / 64, tx, ty, tl);
    } else if (bid < 3328) {
        int r = bid - 3072;          tr32(Wv, WvT, 512, 512, r % 16, r / 16, tx, ty, tl);
    } else if (bid < 3584) {
        int r = bid - 3328;          tr32(Wh, WhT, 512, 512, r % 16, r / 16, tx, ty, tl);
    } else if (bid < 13600) {
        int r = bid - 3584;          tr32(W_out, WoutT, 1024, 10000, r % 313, r / 313, tx, ty, tl);
    } else if (bid < 16160) {
        int r = bid - 13600;         // r = t*128 + b
        int t = r / B_, b = r % B_;
        int tok = cap[b * T_ + t];
        for (int col = tid; col < 2 * H_; col += 256) {
            float v = (col < H_) ? emb[(size_t)tok * H_ + col] : gf[(size_t)b * H_ + (col - H_)];
            X[(size_t)r * (2 * H_) + col] = f2b(v);
        }
    } else if (bid < 20256) {
        // coalesced feat build: per-b 32x32 transpose tiles of area[b][H][F] -> feat[b][F][H]
        int r = bid - 16160;
        int b = r >> 5, t32 = r & 31;
        int fx = t32 & 1, hy = t32 >> 1;
        tr32(area + (size_t)b * H_ * F_, feat + (size_t)b * F_ * H_,
             H_, F_, fx, hy, tx, ty, tl);
    } else {
        int r = bid - 20256;
        int i = r * 256 + tid;                    // covers B_*H_ = 65536
        Hall[i] = f2b(h0[i]);
        if (r < 8) bar[r * 256 + tid] = 0;        // 2048 flag ints
    }
}

// ================= persistent LSTM-only recurrence =================================
// 8 row-groups (mg = bid&7 -> same XCD under round-robin placement) x 16 j-blocks
// (jg = bid>>3, 32 j-cols x 4 gates each). W_hh slice (128 KB) + c-state LDS-resident.
// Barrier: per-producer release FLAG (own 64-B line, monotonic epoch) + 16-lane
// ballot poll + ONE acquire per step (L2 inv -- required for cross-replay safety).
// No atomic RMW serialization. Correctness does not depend on XCD placement.
__global__ __launch_bounds__(256, 1) void decode_loop(
        const u16* __restrict__ WhhT, const float* __restrict__ Xin,
        const float* __restrict__ c0, u16* __restrict__ Hall,
        int* __restrict__ bar) {

    __shared__ __align__(16) u16 Whs[128 * 512];     // 128 KB, XOR-swizzled
    __shared__ __align__(16) u16 hstage[16 * 512];   // 16 KB, XOR-swizzled
    __shared__ float gl[4 * 16 * 32];                // 8 KB gates
    __shared__ float csh[16 * 32];                   // 2 KB c-state (resident)

    const int tid = threadIdx.x;
    const int wave = tid >> 6, lane = tid & 63;
    const int lm = lane & 15, q = lane >> 4;
    const int bid = blockIdx.x;
    const int mg = bid & 7, jg = bid >> 3;

    const int row = tid >> 4, jj = (tid & 15) * 2;   // this thread's 2 LSTM elements
    const int grow = mg * 16 + row;
    const int j = jg * 32 + jj;

    // ---- prologue: Whs (4 gates x 32 j-cols = 128 rows x 512 k) swizzled; c0 ----
    #pragma unroll
    for (int i = 0; i < 32; ++i) {
        int r = i * 4 + wave;                        // 0..127, wave-uniform
        int g = r >> 5, jr = r & 31;
        int wrow = g * H_ + jg * 32 + jr;            // WhhT row (gate-col index)
        load_lds16(WhhT + (size_t)wrow * H_ + (size_t)(lane ^ (r & 7)) * 8,
                   (char*)Whs + r * 1024);
    }
    csh[row * 32 + jj]     = c0[(size_t)grow * H_ + j];
    csh[row * 32 + jj + 1] = c0[(size_t)grow * H_ + j + 1];

    // prefetch Xin for t=0 (float2 per gate)
    floatx2 xf[4];
    {
        const float* xb = Xin + (size_t)grow * (4 * H_) + j;
        #pragma unroll
        for (int g = 0; g < 4; ++g) xf[g] = *(const floatx2*)(xb + g * H_);
    }

    for (int t = 0; t < T_; ++t) {
        const u16* hprev = Hall + (size_t)t * B_ * H_;
        u16* hnext = Hall + (size_t)(t + 1) * B_ * H_;

        // ---- stage h slice (16 rows), pre-swizzled source ----
        #pragma unroll
        for (int i = 0; i < 4; ++i) {
            int r = i * 4 + wave;
            load_lds16(hprev + (size_t)(mg * 16 + r) * H_ + (size_t)(lane ^ (r & 7)) * 8,
                       (char*)hstage + r * 1024);
        }
        __syncthreads();

        // ---- gates MFMA: wave g computes gate g's 16x32 tile ----
        floatx4 acc0 = {0.f, 0.f, 0.f, 0.f}, acc1 = {0.f, 0.f, 0.f, 0.f};
        #pragma unroll
        for (int kt = 0; kt < 16; ++kt) {
            int ch = kt * 4 + q;
            int sw = (ch ^ (lm & 7)) << 3;
            short8 a  = *(const short8*)&hstage[(lm << 9) + sw];
            short8 b0 = *(const short8*)&Whs[((wave * 32 + lm) << 9) + sw];
            short8 b1 = *(const short8*)&Whs[((wave * 32 + 16 + lm) << 9) + sw];
            acc0 = __builtin_amdgcn_mfma_f32_16x16x32_bf16(a, b0, acc0, 0, 0, 0);
            acc1 = __builtin_amdgcn_mfma_f32_16x16x32_bf16(a, b1, acc1, 0, 0, 0);
        }
        #pragma unroll
        for (int r = 0; r < 4; ++r) {
            gl[wave * 512 + (q * 4 + r) * 32 + lm]      = acc0[r];
            gl[wave * 512 + (q * 4 + r) * 32 + 16 + lm] = acc1[r];
        }
        __syncthreads();

        // ---- consume current xf, issue prefetch for t+1 (overlaps LSTM+barrier) ----
        floatx2 xc[4];
        #pragma unroll
        for (int g = 0; g < 4; ++g) xc[g] = xf[g];
        if (t + 1 < T_) {
            const float* xb = Xin + ((size_t)(t + 1) * B_ + grow) * (4 * H_) + j;
            #pragma unroll
            for (int g = 0; g < 4; ++g) xf[g] = *(const floatx2*)(xb + g * H_);
        }

        // ---- LSTM elementwise (2 adjacent elements), h store as packed u32 ----
        {
            float gi0 = gl[0 * 512 + row * 32 + jj]     + xc[0][0];
            float gi1 = gl[0 * 512 + row * 32 + jj + 1] + xc[0][1];
            float gf0 = gl[1 * 512 + row * 32 + jj]     + xc[1][0];
            float gf1 = gl[1 * 512 + row * 32 + jj + 1] + xc[1][1];
            float gg0 = gl[2 * 512 + row * 32 + jj]     + xc[2][0];
            float gg1 = gl[2 * 512 + row * 32 + jj + 1] + xc[2][1];
            float go0 = gl[3 * 512 + row * 32 + jj]     + xc[3][0];
            float go1 = gl[3 * 512 + row * 32 + jj + 1] + xc[3][1];
            float c0n = sigm(gf0) * csh[row * 32 + jj]     + sigm(gi0) * fast_tanh(gg0);
            float c1n = sigm(gf1) * csh[row * 32 + jj + 1] + sigm(gi1) * fast_tanh(gg1);
            csh[row * 32 + jj]     = c0n;
            csh[row * 32 + jj + 1] = c1n;
            unsigned hv = (unsigned)f2b(sigm(go0) * fast_tanh(c0n)) |
                          ((unsigned)f2b(sigm(go1) * fast_tanh(c1n)) << 16);
            *(unsigned*)(hnext + (size_t)grow * H_ + j) = hv;
        }

        // ---- flag barrier: parallel release stores, 16-lane ballot poll ----
        if (t + 1 < T_) {
            __syncthreads();   // all waves' h stores drained (vmcnt 0 before s_barrier)
            if (tid == 0)
                __hip_atomic_store(&bar[(mg * 16 + jg) * 16], t + 1,
                                   __ATOMIC_RELEASE, __HIP_MEMORY_SCOPE_AGENT);
            if (wave == 0) {
                int fl = (lane < 16)
                    ? __hip_atomic_load(&bar[(mg * 16 + lane) * 16],
                                        __ATOMIC_RELAXED, __HIP_MEMORY_SCOPE_AGENT)
                    : (t + 1);
                while (__any(fl < t + 1)) {
                    __builtin_amdgcn_s_sleep(1);
                    fl = (lane < 16)
                        ? __hip_atomic_load(&bar[(mg * 16 + lane) * 16],
                                            __ATOMIC_RELAXED, __HIP_MEMORY_SCOPE_AGENT)
                        : (t + 1);
                }
                if (lane == 0)
                    (void)__hip_atomic_load(&bar[(mg * 16) * 16],
                                            __ATOMIC_ACQUIRE, __HIP_MEMORY_SCOPE_AGENT);
            }
            __syncthreads();
        }
    }
}

// ================= deferred attention: per (b, t-half), all data staged in LDS ======
__global__ __launch_bounds__(256) void attn_post(
        const float* __restrict__ ahbuf, const u16* __restrict__ Vprojb,
        const u16* __restrict__ feat, const float* __restrict__ wo,
        const u16* __restrict__ Hall, u16* __restrict__ Hcat) {
    __shared__ __align__(16) u16 Vsh[F_ * H_];   // 49 KB
    __shared__ __align__(16) u16 fsh[F_ * H_];   // 49 KB
    __shared__ float ash[H_];
    __shared__ float wosh[H_];
    __shared__ float sc[64];

    const int tid = threadIdx.x;
    const int wave = tid >> 6, lane = tid & 63;
    const int b = blockIdx.x >> 1, th = blockIdx.x & 1;

    const short8* vsrc = (const short8*)(Vprojb + (size_t)b * F_ * H_);
    const short8* fsrc = (const short8*)(feat + (size_t)b * F_ * H_);
    for (int i = tid; i < F_ * H_ / 8; i += 256) {
        ((short8*)Vsh)[i] = vsrc[i];
        ((short8*)fsh)[i] = fsrc[i];
    }
    for (int i = tid; i < H_; i += 256) wosh[i] = wo[i];
    __syncthreads();

    for (int t = th * (T_ / 2); t < (th + 1) * (T_ / 2); ++t) {
        for (int i = tid; i < H_; i += 256)
            ash[i] = ahbuf[((size_t)t * B_ + b) * H_ + i];
        __syncthreads();

        for (int f = wave; f < F_; f += 4) {
            short8 vv = *(const short8*)&Vsh[f * H_ + lane * 8];
            float s = 0.f;
            #pragma unroll
            for (int e = 0; e < 8; ++e) {
                int h = lane * 8 + e;
                s += wosh[h] * fast_tanh(b2f((u16)vv[e]) + ash[h]);
            }
            #pragma unroll
            for (int off = 32; off; off >>= 1) s += __shfl_xor(s, off);
            if (lane == 0) sc[f] = s;
        }
        __syncthreads();

        if (tid < 64) {
            float v = (tid < F_) ? sc[tid] : -1e30f;
            float m = v;
            #pragma unroll
            for (int off = 32; off; off >>= 1) m = fmaxf(m, __shfl_xor(m, off));
            float e = (tid < F_) ? __expf(v - m) : 0.f;
            float sum = e;
            #pragma unroll
            for (int off = 32; off; off >>= 1) sum += __shfl_xor(sum, off);
            if (tid < F_) sc[tid] = e / sum;
        }
        __syncthreads();

        const size_t rowo = ((size_t)b * T_ + t) * (2 * H_);
        const short8* hrow = (const short8*)(Hall + ((size_t)(t + 1) * B_ + b) * H_);
        for (int i = tid; i < H_ / 8; i += 256)
            ((short8*)(Hcat + rowo))[i] = hrow[i];
        for (int h = tid; h < H_; h += 256) {
            float acc = 0.f;
            #pragma unroll
            for (int f = 0; f < F_; ++f) acc += b2f(fsh[f * H_ + h]) * sc[f];
            Hcat[rowo + H_ + h] = f2b(acc);
        }
        __syncthreads();
    }
}

// ========== 2-phase double-buffered bf16 MFMA GEMM body (T3-minimum) ===============
template <int WRITE_BF16>
__device__ __forceinline__ void gemm2_body(
        const u16* __restrict__ A, int lda, const u16* __restrict__ Bt, int ldb,
        void* __restrict__ Cout, int ldc, const float* __restrict__ bias1,
        const float* __restrict__ bias2, int M, int N, int K, int bx, int by,
        u16* As, u16* Bs) {
    const int tid = threadIdx.x, wave = tid >> 6, lane = tid & 63;
    const int wr = wave >> 1, wc = wave & 1;
    const int lm = lane & 15, q = lane >> 4;
    const int m0 = bx * 128, n0 = by * 128;

    const int off = wave * 1024 + lane * 16;
    const int r0 = off >> 6;
    const int c0 = (off & 63) >> 1;

    const u16* gA0 = A + (size_t)(m0 + r0) * lda + c0;
    const u16* gA1 = A + (size_t)(m0 + r0 + 64) * lda + c0;
    int nb0 = n0 + r0;      if (nb0 > N - 1) nb0 = N - 1;
    int nb1 = n0 + r0 + 64; if (nb1 > N - 1) nb1 = N - 1;
    const u16* gB0 = Bt + (size_t)nb0 * ldb + c0;
    const u16* gB1 = Bt + (size_t)nb1 * ldb + c0;

    floatx4 acc[4][4];
    #pragma unroll
    for (int i = 0; i < 4; ++i)
        #pragma unroll
        for (int jq = 0; jq < 4; ++jq) acc[i][jq] = floatx4{0.f, 0.f, 0.f, 0.f};

    const int nkt = K >> 5;
    {
        load_lds16(gA0, (char*)As + wave * 1024);
        load_lds16(gA1, (char*)As + 4096 + wave * 1024);
        load_lds16(gB0, (char*)Bs + wave * 1024);
        load_lds16(gB1, (char*)Bs + 4096 + wave * 1024);
    }
    __syncthreads();

    int cur = 0;
    for (int kt = 0; kt < nkt; ++kt) {
        if (kt + 1 < nkt) {
            const int ko = (kt + 1) * 32;
            char* dA = (char*)(As + (cur ^ 1) * 4096);
            char* dB = (char*)(Bs + (cur ^ 1) * 4096);
            load_lds16(gA0 + ko, dA + wave * 1024);
            load_lds16(gA1 + ko, dA + 4096 + wave * 1024);
            load_lds16(gB0 + ko, dB + wave * 1024);
            load_lds16(gB1 + ko, dB + 4096 + wave * 1024);
        }
        const u16* Ab = As + cur * 4096;
        const u16* Bb = Bs + cur * 4096;
        short8 af[4], bf[4];
        #pragma unroll
        for (int i = 0; i < 4; ++i)
            af[i] = *(const short8*)&Ab[(wr * 64 + i * 16 + lm) * 32 + q * 8];
        #pragma unroll
        for (int jq = 0; jq < 4; ++jq)
            bf[jq] = *(const short8*)&Bb[(wc * 64 + jq * 16 + lm) * 32 + q * 8];
        #pragma unroll
        for (int i = 0; i < 4; ++i)
            #pragma unroll
            for (int jq = 0; jq < 4; ++jq)
                acc[i][jq] = __builtin_amdgcn_mfma_f32_16x16x32_bf16(af[i], bf[jq], acc[i][jq], 0, 0, 0);
        __syncthreads();
        cur ^= 1;
    }

    #pragma unroll
    for (int i = 0; i < 4; ++i) {
        const int row = m0 + wr * 64 + i * 16 + q * 4;
        #pragma unroll
        for (int jq = 0; jq < 4; ++jq) {
            const int col = n0 + wc * 64 + jq * 16 + lm;
            if (col < N) {
                #pragma unroll
                for (int r = 0; r < 4; ++r) {
                    float v = acc[i][jq][r];
                    if (bias1) v += bias1[col];
                    if (bias2) v += bias2[col];
                    if (WRITE_BF16) ((u16*)Cout)[(size_t)(row + r) * ldc + col] = f2b(v);
                    else            ((float*)Cout)[(size_t)(row + r) * ldc + col] = v;
                }
            }
        }
    }
}

// standalone GEMM with bijective XCD-chunk swizzle (m204) for B-panel L2 locality
template <int WRITE_BF16>
__global__ __launch_bounds__(256) void gemm2(const u16* __restrict__ A, int lda,
                                             const u16* __restrict__ Bt, int ldb,
                                             void* __restrict__ Cout, int ldc,
                                             const float* __restrict__ bias1,
                                             const float* __restrict__ bias2,
                                             int M, int N, int K) {
    __shared__ __align__(16) u16 As[2 * 128 * 32];
    __shared__ __align__(16) u16 Bs[2 * 128 * 32];
    const int nbx = gridDim.x;
    const int nwg = nbx * gridDim.y;
    const int lin = blockIdx.x + blockIdx.y * nbx;
    const int qq = nwg >> 3, rr = nwg & 7;
    const int xcd = lin & 7, idx = lin >> 3;
    const int wg = (xcd < rr ? xcd * (qq + 1) : rr * (qq + 1) + (xcd - rr) * qq) + idx;
    gemm2_body<WRITE_BF16>(A, lda, Bt, ldb, Cout, ldc, bias1, bias2, M, N, K,
                           wg % nbx, wg / nbx, As, Bs);
}

// ---- grouped: Xin = X@W_ih + biases (320 blocks) ; Vproj = feat@Wv (196 blocks) ----
__global__ __launch_bounds__(256) void gemm_pair(
        const u16* __restrict__ X, const u16* __restrict__ WihT,
        float* __restrict__ Xin, const float* __restrict__ b_ih,
        const float* __restrict__ b_hh, const u16* __restrict__ feat,
        const u16* __restrict__ WvT, u16* __restrict__ Vprojb) {
    __shared__ __align__(16) u16 As[2 * 128 * 32];
    __shared__ __align__(16) u16 Bs[2 * 128 * 32];
    int bid = blockIdx.x;
    if (bid < 320) {
        gemm2_body<0>(X, 2 * H_, WihT, 2 * H_, Xin, 4 * H_, b_ih, b_hh,
                      T_ * B_, 4 * H_, 2 * H_, bid % 20, bid / 20, As, Bs);
    } else {
        int r = bid - 320;
        gemm2_body<1>(feat, H_, WvT, H_, Vprojb, H_, nullptr, nullptr,
                      B_ * F_, H_, H_, r % 49, r / 49, As, Bs);
    }
}

extern "C" void kernel_launch(void* const* d_in, const int* in_sizes, int n_in,
                              void* d_out, int out_size, void* d_ws, size_t ws_size,
                              hipStream_t stream) {
    const int*   cap   = (const int*)d_in[0];
    const float* gf    = (const float*)d_in[1];
    const float* area  = (const float*)d_in[2];
    const float* h0    = (const float*)d_in[3];
    const float* c0    = (const float*)d_in[4];
    const float* emb   = (const float*)d_in[5];
    const float* W_ih  = (const float*)d_in[6];
    const float* W_hh  = (const float*)d_in[7];
    const float* b_ih  = (const float*)d_in[8];
    const float* b_hh  = (const float*)d_in[9];
    const float* Wv    = (const float*)d_in[10];
    const float* Wh    = (const float*)d_in[11];
    const float* wo    = (const float*)d_in[12];
    const float* W_out = (const float*)d_in[13];
    const float* b_out = (const float*)d_in[14];
    float* out = (float*)d_out;

    char* p = (char*)d_ws;
    auto alloc = [&](size_t bytes) {
        char* q = p;
        p += (bytes + 255) & ~(size_t)255;
        return q;
    };
    u16*   X      = (u16*)alloc((size_t)T_ * B_ * 2 * H_ * 2);     // [2560,1024]
    u16*   WihT   = (u16*)alloc((size_t)4 * H_ * 2 * H_ * 2);      // [2048,1024]
    u16*   WhhT   = (u16*)alloc((size_t)4 * H_ * H_ * 2);          // [2048,512]
    u16*   WvT    = (u16*)alloc((size_t)H_ * H_ * 2);              // [512,512]
    u16*   WhT    = (u16*)alloc((size_t)H_ * H_ * 2);              // [512,512]
    u16*   WoutT  = (u16*)alloc((size_t)V_ * 2 * H_ * 2);          // [10000,1024]
    u16*   feat   = (u16*)alloc((size_t)B_ * F_ * H_ * 2);         // [6272,512]
    float* Xin    = (float*)alloc((size_t)T_ * B_ * 4 * H_ * 4);   // [2560,2048] f32
    u16*   Vprojb = (u16*)alloc((size_t)B_ * F_ * H_ * 2);         // [6272,512] bf16
    float* ahbuf  = (float*)alloc((size_t)T_ * B_ * H_ * 4);       // [2560,512] f32
    u16*   Hall   = (u16*)alloc((size_t)(T_ + 1) * B_ * H_ * 2);   // [21,128,512]
    int*   bar    = (int*)alloc(8192);                             // 128 flags x 64 B
    u16*   Hcat   = (u16*)alloc((size_t)B_ * T_ * 2 * H_ * 2);     // [2560,1024]

    // 1) fused preamble
    preamble<<<20512, 256, 0, stream>>>(W_ih, W_hh, Wv, Wh, W_out, cap, emb, gf,
                                        area, h0, WihT, WhhT, WvT, WhT, WoutT,
                                        X, feat, Hall, bar);

    // 2) grouped Xin-GEMM + Vproj-GEMM
    gemm_pair<<<516, 256, 0, stream>>>(X, WihT, Xin, b_ih, b_hh, feat, WvT, Vprojb);

    // 3) LSTM-only persistent recurrence (flag barrier, 8x16 XCD-aligned groups)
    decode_loop<<<NBLK_, 256, 0, stream>>>(WhhT, Xin, c0, Hall, bar);

    // 4) ah_all = Hall[1..T] @ Wh   [2560,512] f32
    gemm2<0><<<dim3(T_ * B_ / 128, H_ / 128), 256, 0, stream>>>(
        Hall + (size_t)B_ * H_, H_, WhT, H_, ahbuf, H_, nullptr, nullptr, T_ * B_, H_, H_);

    // 5) scores/softmax/attended + Hcat assembly
    attn_post<<<2 * B_, 256, 0, stream>>>(ahbuf, Vprojb, feat, wo, Hall, Hcat);

    // 6) out = Hcat @ W_out + b_out   [2560,10000] f32
    gemm2<0><<<dim3(T_ * B_ / 128, (V_ + 127) / 128), 256, 0, stream>>>(
        Hcat, 2 * H_, WoutT, 2 * H_, out, V_, b_out, nullptr, T_ * B_, V_, 2 * H_);
}

// Round 9
// 561.176 us; speedup vs baseline: 3.1858x; 1.0142x over previous
//
#include <hip/hip_runtime.h>

#define B_ 128
#define T_ 20
#define V_ 10000
#define H_ 512
#define F_ 49
#define NBLK_ 128

typedef unsigned short u16;
typedef __attribute__((ext_vector_type(8))) short short8;
typedef __attribute__((ext_vector_type(4))) float floatx4;
typedef __attribute__((ext_vector_type(2))) float floatx2;

#define GLOBAL_AS __attribute__((address_space(1)))
#define LDS_AS    __attribute__((address_space(3)))

__device__ inline void load_lds16(const void* g, void* l) {
    __builtin_amdgcn_global_load_lds((const GLOBAL_AS void*)g, (LDS_AS void*)l, 16, 0, 0);
}

// fp32 -> bf16 round-to-nearest-even
__device__ inline u16 f2b(float v) {
    unsigned u = __builtin_bit_cast(unsigned, v);
    unsigned rounding = 0x7FFFu + ((u >> 16) & 1u);
    return (u16)((u + rounding) >> 16);
}
__device__ inline float b2f(u16 h) {
    unsigned u = ((unsigned)h) << 16;
    return __builtin_bit_cast(float, u);
}
__device__ inline float fast_tanh(float x) {
    return 1.f - 2.f / (__expf(2.f * x) + 1.f);
}
__device__ inline float sigm(float x) { return 1.f / (1.f + __expf(-x)); }

// ---------------- 32x32 transpose+cvt tile (device fn; block-uniform call) ----------
__device__ __forceinline__ void tr32(const float* __restrict__ src, u16* __restrict__ dst,
                                     int K, int N, int bx, int by, int tx, int ty,
                                     float (*tl)[33]) {
    int n0 = bx * 32, k0 = by * 32;
    #pragma unroll
    for (int i = 0; i < 32; i += 8) {
        int k = k0 + ty + i, n = n0 + tx;
        tl[ty + i][tx] = (k < K && n < N) ? src[(size_t)k * N + n] : 0.f;
    }
    __syncthreads();
    #pragma unroll
    for (int i = 0; i < 32; i += 8) {
        int n = n0 + ty + i, k = k0 + tx;
        if (n < N && k < K) dst[(size_t)n * K + k] = f2b(tl[tx][ty + i]);
    }
}

// ================= fused preamble: all transposes + build_x + feat-transpose + init =
__global__ __launch_bounds__(256) void preamble(
        const float* __restrict__ W_ih, const float* __restrict__ W_hh,
        const float* __restrict__ Wv, const float* __restrict__ Wh,
        const float* __restrict__ W_out, const int* __restrict__ cap,
        const float* __restrict__ emb, const float* __restrict__ gf,
        const float* __restrict__ area, const float* __restrict__ h0,
        u16* __restrict__ WihT, u16* __restrict__ WhhT, u16* __restrict__ WvT,
        u16* __restrict__ WhT, u16* __restrict__ WoutT, u16* __restrict__ X,
        u16* __restrict__ feat, u16* __restrict__ Hall, int* __restrict__ bar) {
    __shared__ float tl[32][33];
    const int bid = blockIdx.x, tid = threadIdx.x;
    const int tx = tid & 31, ty = tid >> 5;

    if (bid < 2048) {
        int r = bid;                 tr32(W_ih, WihT, 1024, 2048, r % 64, r / 64, tx, ty, tl);
    } else if (bid < 3072) {
        int r = bid - 2048;          tr32(W_hh, WhhT, 512, 2048, r % 64, r / 64, tx, ty, tl);
    } else if (bid < 3328) {
        int r = bid - 3072;          tr32(Wv, WvT, 512, 512, r % 16, r / 16, tx, ty, tl);
    } else if (bid < 3584) {
        int r = bid - 3328;          tr32(Wh, WhT, 512, 512, r % 16, r / 16, tx, ty, tl);
    } else if (bid < 13600) {
        int r = bid - 3584;          tr32(W_out, WoutT, 1024, 10000, r % 313, r / 313, tx, ty, tl);
    } else if (bid < 16160) {
        int r = bid - 13600;         // r = t*128 + b
        int t = r / B_, b = r % B_;
        int tok = cap[b * T_ + t];
        for (int col = tid; col < 2 * H_; col += 256) {
            float v = (col < H_) ? emb[(size_t)tok * H_ + col] : gf[(size_t)b * H_ + (col - H_)];
            X[(size_t)r * (2 * H_) + col] = f2b(v);
        }
    } else if (bid < 20256) {
        int r = bid - 16160;
        int b = r >> 5, t32 = r & 31;
        int fx = t32 & 1, hy = t32 >> 1;
        tr32(area + (size_t)b * H_ * F_, feat + (size_t)b * F_ * H_,
             H_, F_, fx, hy, tx, ty, tl);
    } else {
        int r = bid - 20256;
        int i = r * 256 + tid;                    // covers B_*H_ = 65536
        Hall[i] = f2b(h0[i]);
        if (r < 8) bar[r * 256 + tid] = 0;        // 2048 flag ints
    }
}

// ================= persistent LSTM-only recurrence (unchanged from R8) =============
__global__ __launch_bounds__(256, 1) void decode_loop(
        const u16* __restrict__ WhhT, const float* __restrict__ Xin,
        const float* __restrict__ c0, u16* __restrict__ Hall,
        int* __restrict__ bar) {

    __shared__ __align__(16) u16 Whs[128 * 512];     // 128 KB, XOR-swizzled
    __shared__ __align__(16) u16 hstage[16 * 512];   // 16 KB, XOR-swizzled
    __shared__ float gl[4 * 16 * 32];                // 8 KB gates
    __shared__ float csh[16 * 32];                   // 2 KB c-state (resident)

    const int tid = threadIdx.x;
    const int wave = tid >> 6, lane = tid & 63;
    const int lm = lane & 15, q = lane >> 4;
    const int bid = blockIdx.x;
    const int mg = bid & 7, jg = bid >> 3;

    const int row = tid >> 4, jj = (tid & 15) * 2;
    const int grow = mg * 16 + row;
    const int j = jg * 32 + jj;

    #pragma unroll
    for (int i = 0; i < 32; ++i) {
        int r = i * 4 + wave;
        int g = r >> 5, jr = r & 31;
        int wrow = g * H_ + jg * 32 + jr;
        load_lds16(WhhT + (size_t)wrow * H_ + (size_t)(lane ^ (r & 7)) * 8,
                   (char*)Whs + r * 1024);
    }
    csh[row * 32 + jj]     = c0[(size_t)grow * H_ + j];
    csh[row * 32 + jj + 1] = c0[(size_t)grow * H_ + j + 1];

    floatx2 xf[4];
    {
        const float* xb = Xin + (size_t)grow * (4 * H_) + j;
        #pragma unroll
        for (int g = 0; g < 4; ++g) xf[g] = *(const floatx2*)(xb + g * H_);
    }

    for (int t = 0; t < T_; ++t) {
        const u16* hprev = Hall + (size_t)t * B_ * H_;
        u16* hnext = Hall + (size_t)(t + 1) * B_ * H_;

        #pragma unroll
        for (int i = 0; i < 4; ++i) {
            int r = i * 4 + wave;
            load_lds16(hprev + (size_t)(mg * 16 + r) * H_ + (size_t)(lane ^ (r & 7)) * 8,
                       (char*)hstage + r * 1024);
        }
        __syncthreads();

        floatx4 acc0 = {0.f, 0.f, 0.f, 0.f}, acc1 = {0.f, 0.f, 0.f, 0.f};
        #pragma unroll
        for (int kt = 0; kt < 16; ++kt) {
            int ch = kt * 4 + q;
            int sw = (ch ^ (lm & 7)) << 3;
            short8 a  = *(const short8*)&hstage[(lm << 9) + sw];
            short8 b0 = *(const short8*)&Whs[((wave * 32 + lm) << 9) + sw];
            short8 b1 = *(const short8*)&Whs[((wave * 32 + 16 + lm) << 9) + sw];
            acc0 = __builtin_amdgcn_mfma_f32_16x16x32_bf16(a, b0, acc0, 0, 0, 0);
            acc1 = __builtin_amdgcn_mfma_f32_16x16x32_bf16(a, b1, acc1, 0, 0, 0);
        }
        #pragma unroll
        for (int r = 0; r < 4; ++r) {
            gl[wave * 512 + (q * 4 + r) * 32 + lm]      = acc0[r];
            gl[wave * 512 + (q * 4 + r) * 32 + 16 + lm] = acc1[r];
        }
        __syncthreads();

        floatx2 xc[4];
        #pragma unroll
        for (int g = 0; g < 4; ++g) xc[g] = xf[g];
        if (t + 1 < T_) {
            const float* xb = Xin + ((size_t)(t + 1) * B_ + grow) * (4 * H_) + j;
            #pragma unroll
            for (int g = 0; g < 4; ++g) xf[g] = *(const floatx2*)(xb + g * H_);
        }

        {
            float gi0 = gl[0 * 512 + row * 32 + jj]     + xc[0][0];
            float gi1 = gl[0 * 512 + row * 32 + jj + 1] + xc[0][1];
            float gf0 = gl[1 * 512 + row * 32 + jj]     + xc[1][0];
            float gf1 = gl[1 * 512 + row * 32 + jj + 1] + xc[1][1];
            float gg0 = gl[2 * 512 + row * 32 + jj]     + xc[2][0];
            float gg1 = gl[2 * 512 + row * 32 + jj + 1] + xc[2][1];
            float go0 = gl[3 * 512 + row * 32 + jj]     + xc[3][0];
            float go1 = gl[3 * 512 + row * 32 + jj + 1] + xc[3][1];
            float c0n = sigm(gf0) * csh[row * 32 + jj]     + sigm(gi0) * fast_tanh(gg0);
            float c1n = sigm(gf1) * csh[row * 32 + jj + 1] + sigm(gi1) * fast_tanh(gg1);
            csh[row * 32 + jj]     = c0n;
            csh[row * 32 + jj + 1] = c1n;
            unsigned hv = (unsigned)f2b(sigm(go0) * fast_tanh(c0n)) |
                          ((unsigned)f2b(sigm(go1) * fast_tanh(c1n)) << 16);
            *(unsigned*)(hnext + (size_t)grow * H_ + j) = hv;
        }

        if (t + 1 < T_) {
            __syncthreads();
            if (tid == 0)
                __hip_atomic_store(&bar[(mg * 16 + jg) * 16], t + 1,
                                   __ATOMIC_RELEASE, __HIP_MEMORY_SCOPE_AGENT);
            if (wave == 0) {
                int fl = (lane < 16)
                    ? __hip_atomic_load(&bar[(mg * 16 + lane) * 16],
                                        __ATOMIC_RELAXED, __HIP_MEMORY_SCOPE_AGENT)
                    : (t + 1);
                while (__any(fl < t + 1)) {
                    __builtin_amdgcn_s_sleep(1);
                    fl = (lane < 16)
                        ? __hip_atomic_load(&bar[(mg * 16 + lane) * 16],
                                            __ATOMIC_RELAXED, __HIP_MEMORY_SCOPE_AGENT)
                        : (t + 1);
                }
                if (lane == 0)
                    (void)__hip_atomic_load(&bar[(mg * 16) * 16],
                                            __ATOMIC_ACQUIRE, __HIP_MEMORY_SCOPE_AGENT);
            }
            __syncthreads();
        }
    }
}

// ================= deferred attention (unchanged from R8) ==========================
__global__ __launch_bounds__(256) void attn_post(
        const float* __restrict__ ahbuf, const u16* __restrict__ Vprojb,
        const u16* __restrict__ feat, const float* __restrict__ wo,
        const u16* __restrict__ Hall, u16* __restrict__ Hcat) {
    __shared__ __align__(16) u16 Vsh[F_ * H_];
    __shared__ __align__(16) u16 fsh[F_ * H_];
    __shared__ float ash[H_];
    __shared__ float wosh[H_];
    __shared__ float sc[64];

    const int tid = threadIdx.x;
    const int wave = tid >> 6, lane = tid & 63;
    const int b = blockIdx.x >> 1, th = blockIdx.x & 1;

    const short8* vsrc = (const short8*)(Vprojb + (size_t)b * F_ * H_);
    const short8* fsrc = (const short8*)(feat + (size_t)b * F_ * H_);
    for (int i = tid; i < F_ * H_ / 8; i += 256) {
        ((short8*)Vsh)[i] = vsrc[i];
        ((short8*)fsh)[i] = fsrc[i];
    }
    for (int i = tid; i < H_; i += 256) wosh[i] = wo[i];
    __syncthreads();

    for (int t = th * (T_ / 2); t < (th + 1) * (T_ / 2); ++t) {
        for (int i = tid; i < H_; i += 256)
            ash[i] = ahbuf[((size_t)t * B_ + b) * H_ + i];
        __syncthreads();

        for (int f = wave; f < F_; f += 4) {
            short8 vv = *(const short8*)&Vsh[f * H_ + lane * 8];
            float s = 0.f;
            #pragma unroll
            for (int e = 0; e < 8; ++e) {
                int h = lane * 8 + e;
                s += wosh[h] * fast_tanh(b2f((u16)vv[e]) + ash[h]);
            }
            #pragma unroll
            for (int off = 32; off; off >>= 1) s += __shfl_xor(s, off);
            if (lane == 0) sc[f] = s;
        }
        __syncthreads();

        if (tid < 64) {
            float v = (tid < F_) ? sc[tid] : -1e30f;
            float m = v;
            #pragma unroll
            for (int off = 32; off; off >>= 1) m = fmaxf(m, __shfl_xor(m, off));
            float e = (tid < F_) ? __expf(v - m) : 0.f;
            float sum = e;
            #pragma unroll
            for (int off = 32; off; off >>= 1) sum += __shfl_xor(sum, off);
            if (tid < F_) sc[tid] = e / sum;
        }
        __syncthreads();

        const size_t rowo = ((size_t)b * T_ + t) * (2 * H_);
        const short8* hrow = (const short8*)(Hall + ((size_t)(t + 1) * B_ + b) * H_);
        for (int i = tid; i < H_ / 8; i += 256)
            ((short8*)(Hcat + rowo))[i] = hrow[i];
        for (int h = tid; h < H_; h += 256) {
            float acc = 0.f;
            #pragma unroll
            for (int f = 0; f < F_; ++f) acc += b2f(fsh[f * H_ + h]) * sc[f];
            Hcat[rowo + H_ + h] = f2b(acc);
        }
        __syncthreads();
    }
}

// ========== 2-phase double-buffered bf16 MFMA GEMM body (128x128, unchanged) =======
template <int WRITE_BF16>
__device__ __forceinline__ void gemm2_body(
        const u16* __restrict__ A, int lda, const u16* __restrict__ Bt, int ldb,
        void* __restrict__ Cout, int ldc, const float* __restrict__ bias1,
        const float* __restrict__ bias2, int M, int N, int K, int bx, int by,
        u16* As, u16* Bs) {
    const int tid = threadIdx.x, wave = tid >> 6, lane = tid & 63;
    const int wr = wave >> 1, wc = wave & 1;
    const int lm = lane & 15, q = lane >> 4;
    const int m0 = bx * 128, n0 = by * 128;

    const int off = wave * 1024 + lane * 16;
    const int r0 = off >> 6;
    const int c0 = (off & 63) >> 1;

    const u16* gA0 = A + (size_t)(m0 + r0) * lda + c0;
    const u16* gA1 = A + (size_t)(m0 + r0 + 64) * lda + c0;
    int nb0 = n0 + r0;      if (nb0 > N - 1) nb0 = N - 1;
    int nb1 = n0 + r0 + 64; if (nb1 > N - 1) nb1 = N - 1;
    const u16* gB0 = Bt + (size_t)nb0 * ldb + c0;
    const u16* gB1 = Bt + (size_t)nb1 * ldb + c0;

    floatx4 acc[4][4];
    #pragma unroll
    for (int i = 0; i < 4; ++i)
        #pragma unroll
        for (int jq = 0; jq < 4; ++jq) acc[i][jq] = floatx4{0.f, 0.f, 0.f, 0.f};

    const int nkt = K >> 5;
    {
        load_lds16(gA0, (char*)As + wave * 1024);
        load_lds16(gA1, (char*)As + 4096 + wave * 1024);
        load_lds16(gB0, (char*)Bs + wave * 1024);
        load_lds16(gB1, (char*)Bs + 4096 + wave * 1024);
    }
    __syncthreads();

    int cur = 0;
    for (int kt = 0; kt < nkt; ++kt) {
        if (kt + 1 < nkt) {
            const int ko = (kt + 1) * 32;
            char* dA = (char*)(As + (cur ^ 1) * 4096);
            char* dB = (char*)(Bs + (cur ^ 1) * 4096);
            load_lds16(gA0 + ko, dA + wave * 1024);
            load_lds16(gA1 + ko, dA + 4096 + wave * 1024);
            load_lds16(gB0 + ko, dB + wave * 1024);
            load_lds16(gB1 + ko, dB + 4096 + wave * 1024);
        }
        const u16* Ab = As + cur * 4096;
        const u16* Bb = Bs + cur * 4096;
        short8 af[4], bf[4];
        #pragma unroll
        for (int i = 0; i < 4; ++i)
            af[i] = *(const short8*)&Ab[(wr * 64 + i * 16 + lm) * 32 + q * 8];
        #pragma unroll
        for (int jq = 0; jq < 4; ++jq)
            bf[jq] = *(const short8*)&Bb[(wc * 64 + jq * 16 + lm) * 32 + q * 8];
        #pragma unroll
        for (int i = 0; i < 4; ++i)
            #pragma unroll
            for (int jq = 0; jq < 4; ++jq)
                acc[i][jq] = __builtin_amdgcn_mfma_f32_16x16x32_bf16(af[i], bf[jq], acc[i][jq], 0, 0, 0);
        __syncthreads();
        cur ^= 1;
    }

    #pragma unroll
    for (int i = 0; i < 4; ++i) {
        const int row = m0 + wr * 64 + i * 16 + q * 4;
        #pragma unroll
        for (int jq = 0; jq < 4; ++jq) {
            const int col = n0 + wc * 64 + jq * 16 + lm;
            if (col < N) {
                #pragma unroll
                for (int r = 0; r < 4; ++r) {
                    float v = acc[i][jq][r];
                    if (bias1) v += bias1[col];
                    if (bias2) v += bias2[col];
                    if (WRITE_BF16) ((u16*)Cout)[(size_t)(row + r) * ldc + col] = f2b(v);
                    else            ((float*)Cout)[(size_t)(row + r) * ldc + col] = v;
                }
            }
        }
    }
}

template <int WRITE_BF16>
__global__ __launch_bounds__(256) void gemm2(const u16* __restrict__ A, int lda,
                                             const u16* __restrict__ Bt, int ldb,
                                             void* __restrict__ Cout, int ldc,
                                             const float* __restrict__ bias1,
                                             const float* __restrict__ bias2,
                                             int M, int N, int K) {
    __shared__ __align__(16) u16 As[2 * 128 * 32];
    __shared__ __align__(16) u16 Bs[2 * 128 * 32];
    const int nbx = gridDim.x;
    const int nwg = nbx * gridDim.y;
    const int lin = blockIdx.x + blockIdx.y * nbx;
    const int qq = nwg >> 3, rr = nwg & 7;
    const int xcd = lin & 7, idx = lin >> 3;
    const int wg = (xcd < rr ? xcd * (qq + 1) : rr * (qq + 1) + (xcd - rr) * qq) + idx;
    gemm2_body<WRITE_BF16>(A, lda, Bt, ldb, Cout, ldc, bias1, bias2, M, N, K,
                           wg % nbx, wg / nbx, As, Bs);
}

// ---- grouped: Xin = X@W_ih + biases (320 blocks) ; Vproj = feat@Wv (196 blocks) ----
__global__ __launch_bounds__(256) void gemm_pair(
        const u16* __restrict__ X, const u16* __restrict__ WihT,
        float* __restrict__ Xin, const float* __restrict__ b_ih,
        const float* __restrict__ b_hh, const u16* __restrict__ feat,
        const u16* __restrict__ WvT, u16* __restrict__ Vprojb) {
    __shared__ __align__(16) u16 As[2 * 128 * 32];
    __shared__ __align__(16) u16 Bs[2 * 128 * 32];
    int bid = blockIdx.x;
    if (bid < 320) {
        gemm2_body<0>(X, 2 * H_, WihT, 2 * H_, Xin, 4 * H_, b_ih, b_hh,
                      T_ * B_, 4 * H_, 2 * H_, bid % 20, bid / 20, As, Bs);
    } else {
        int r = bid - 320;
        gemm2_body<1>(feat, H_, WvT, H_, Vprojb, H_, nullptr, nullptr,
                      B_ * F_, H_, H_, r % 49, r / 49, As, Bs);
    }
}

// ========== 256x256 8-wave BK=64 phase-split GEMM for the output projection ========
// f32 out = A[M,K] @ Bt[N,K]^T + bias1. LDS: 2 dbuf x 32 KB per operand = 128 KB,
// chunk-XOR swizzle (phys 16B-chunk = logical ^ (row&7)) via pre-swizzled global
// source (G21; same scheme verified in decode_loop). 4 phases per K-tile, next-tile
// staging issued at phase 1 (4 phases ~ 320-640 cyc to land), single vmcnt(0)+barrier
// per K-tile (T3-minimum at 256^2), setprio around MFMA clusters (T5).
__global__ __launch_bounds__(512, 1) void gemm_out(
        const u16* __restrict__ A, int lda, const u16* __restrict__ Bt, int ldb,
        float* __restrict__ Cout, int ldc, const float* __restrict__ bias1,
        int M, int N, int K) {
    __shared__ __align__(16) u16 As[2 * 16384];   // 64 KB: [dbuf][256 rows][64 k]
    __shared__ __align__(16) u16 Bs[2 * 16384];   // 64 KB

    const int tid = threadIdx.x;
    const int wave = tid >> 6, lane = tid & 63;
    const int lm = lane & 15, q = lane >> 4;
    const int wm = wave >> 2, wn = wave & 3;      // 2M x 4N wave grid

    // XCD-chunk swizzle (bijective; nwg = gridDim.x*gridDim.y)
    const int nbx = gridDim.x;
    const int nwg = nbx * gridDim.y;
    const int lin = blockIdx.x + blockIdx.y * nbx;
    const int qq = nwg >> 3, rr = nwg & 7;
    const int xcd = lin & 7, idx = lin >> 3;
    const int wg = (xcd < rr ? xcd * (qq + 1) : rr * (qq + 1) + (xcd - rr) * qq) + idx;
    const int m0 = (wg % nbx) * 256, n0 = (wg / nbx) * 256;

    const int r8 = lane >> 3;                     // row-in-8 AND (row&7) for staged rows
    const int gch = (lane & 7) ^ r8;              // pre-swizzled global chunk

    floatx4 acc[8][4];
    #pragma unroll
    for (int i = 0; i < 8; ++i)
        #pragma unroll
        for (int jn = 0; jn < 4; ++jn) acc[i][jn] = floatx4{0.f, 0.f, 0.f, 0.f};

    const int nkt = K >> 6;                       // BK = 64

    // STAGE tile kt2 into buffer kt2&1: A 4 rounds + B 4 rounds of global_load_lds
    auto STAGE = [&](int kt2) {
        u16* Ad = As + (kt2 & 1) * 16384;
        u16* Bd = Bs + (kt2 & 1) * 16384;
        const int kb = kt2 * 64;
        #pragma unroll
        for (int i = 0; i < 4; ++i) {
            int rw = i * 8 + wave;                // wave-uniform 1 KB slot (8 rows)
            int rowA = rw * 8 + r8;               // 0..255
            load_lds16(A + (size_t)(m0 + rowA) * lda + kb + gch * 8,
                       (char*)Ad + rw * 1024);
        }
        #pragma unroll
        for (int i = 0; i < 4; ++i) {
            int rw = i * 8 + wave;
            int rowB = rw * 8 + r8;
            int nb = n0 + rowB; if (nb > N - 1) nb = N - 1;
            load_lds16(Bt + (size_t)nb * ldb + kb + gch * 8,
                       (char*)Bd + rw * 1024);
        }
    };

    STAGE(0);
    __syncthreads();                              // full drain once (prologue)

    for (int kt = 0; kt < nkt; ++kt) {
        const u16* Ab = As + (kt & 1) * 16384;
        const u16* Bb = Bs + (kt & 1) * 16384;
        if (kt + 1 < nkt) STAGE(kt + 1);          // issue-early: 4 phases to land

        #pragma unroll
        for (int kk = 0; kk < 2; ++kk) {
            const int chs = ((kk * 4 + q) ^ (lm & 7)) * 8;   // swizzled chunk (u16 idx)
            short8 bF[4];
            #pragma unroll
            for (int fn = 0; fn < 4; ++fn)
                bF[fn] = *(const short8*)(Bb + (size_t)(wn * 64 + fn * 16 + lm) * 64 + chs);
            #pragma unroll
            for (int mh = 0; mh < 2; ++mh) {
                short8 aF[4];
                #pragma unroll
                for (int f = 0; f < 4; ++f)
                    aF[f] = *(const short8*)(Ab + (size_t)(wm * 128 + mh * 64 + f * 16 + lm) * 64 + chs);
                __builtin_amdgcn_s_barrier();     // phase lockstep (no waitcnt)
                __builtin_amdgcn_s_setprio(1);
                #pragma unroll
                for (int f = 0; f < 4; ++f)
                    #pragma unroll
                    for (int fn = 0; fn < 4; ++fn)
                        acc[mh * 4 + f][fn] = __builtin_amdgcn_mfma_f32_16x16x32_bf16(
                            aF[f], bF[fn], acc[mh * 4 + f][fn], 0, 0, 0);
                __builtin_amdgcn_s_setprio(0);
                __builtin_amdgcn_s_barrier();
            }
        }
        // tile boundary: my staged loads landed; cross-wave ordered by barrier
        asm volatile("s_waitcnt vmcnt(0)" ::: "memory");
        __builtin_amdgcn_s_barrier();
    }

    #pragma unroll
    for (int fm = 0; fm < 8; ++fm) {
        const int row = m0 + wm * 128 + fm * 16 + q * 4;
        #pragma unroll
        for (int fn = 0; fn < 4; ++fn) {
            const int col = n0 + wn * 64 + fn * 16 + lm;
            if (col < N) {
                float bv = bias1[col];
                #pragma unroll
                for (int r = 0; r < 4; ++r)
                    Cout[(size_t)(row + r) * ldc + col] = acc[fm][fn][r] + bv;
            }
        }
    }
}

extern "C" void kernel_launch(void* const* d_in, const int* in_sizes, int n_in,
                              void* d_out, int out_size, void* d_ws, size_t ws_size,
                              hipStream_t stream) {
    const int*   cap   = (const int*)d_in[0];
    const float* gf    = (const float*)d_in[1];
    const float* area  = (const float*)d_in[2];
    const float* h0    = (const float*)d_in[3];
    const float* c0    = (const float*)d_in[4];
    const float* emb   = (const float*)d_in[5];
    const float* W_ih  = (const float*)d_in[6];
    const float* W_hh  = (const float*)d_in[7];
    const float* b_ih  = (const float*)d_in[8];
    const float* b_hh  = (const float*)d_in[9];
    const float* Wv    = (const float*)d_in[10];
    const float* Wh    = (const float*)d_in[11];
    const float* wo    = (const float*)d_in[12];
    const float* W_out = (const float*)d_in[13];
    const float* b_out = (const float*)d_in[14];
    float* out = (float*)d_out;

    char* p = (char*)d_ws;
    auto alloc = [&](size_t bytes) {
        char* q = p;
        p += (bytes + 255) & ~(size_t)255;
        return q;
    };
    u16*   X      = (u16*)alloc((size_t)T_ * B_ * 2 * H_ * 2);     // [2560,1024]
    u16*   WihT   = (u16*)alloc((size_t)4 * H_ * 2 * H_ * 2);      // [2048,1024]
    u16*   WhhT   = (u16*)alloc((size_t)4 * H_ * H_ * 2);          // [2048,512]
    u16*   WvT    = (u16*)alloc((size_t)H_ * H_ * 2);              // [512,512]
    u16*   WhT    = (u16*)alloc((size_t)H_ * H_ * 2);              // [512,512]
    u16*   WoutT  = (u16*)alloc((size_t)V_ * 2 * H_ * 2);          // [10000,1024]
    u16*   feat   = (u16*)alloc((size_t)B_ * F_ * H_ * 2);         // [6272,512]
    float* Xin    = (float*)alloc((size_t)T_ * B_ * 4 * H_ * 4);   // [2560,2048] f32
    u16*   Vprojb = (u16*)alloc((size_t)B_ * F_ * H_ * 2);         // [6272,512] bf16
    float* ahbuf  = (float*)alloc((size_t)T_ * B_ * H_ * 4);       // [2560,512] f32
    u16*   Hall   = (u16*)alloc((size_t)(T_ + 1) * B_ * H_ * 2);   // [21,128,512]
    int*   bar    = (int*)alloc(8192);                             // 128 flags x 64 B
    u16*   Hcat   = (u16*)alloc((size_t)B_ * T_ * 2 * H_ * 2);     // [2560,1024]

    // 1) fused preamble
    preamble<<<20512, 256, 0, stream>>>(W_ih, W_hh, Wv, Wh, W_out, cap, emb, gf,
                                        area, h0, WihT, WhhT, WvT, WhT, WoutT,
                                        X, feat, Hall, bar);

    // 2) grouped Xin-GEMM + Vproj-GEMM
    gemm_pair<<<516, 256, 0, stream>>>(X, WihT, Xin, b_ih, b_hh, feat, WvT, Vprojb);

    // 3) LSTM-only persistent recurrence (flag barrier, 8x16 XCD-aligned groups)
    decode_loop<<<NBLK_, 256, 0, stream>>>(WhhT, Xin, c0, Hall, bar);

    // 4) ah_all = Hall[1..T] @ Wh   [2560,512] f32
    gemm2<0><<<dim3(T_ * B_ / 128, H_ / 128), 256, 0, stream>>>(
        Hall + (size_t)B_ * H_, H_, WhT, H_, ahbuf, H_, nullptr, nullptr, T_ * B_, H_, H_);

    // 5) scores/softmax/attended + Hcat assembly
    attn_post<<<2 * B_, 256, 0, stream>>>(ahbuf, Vprojb, feat, wo, Hall, Hcat);

    // 6) out = Hcat @ W_out + b_out  [2560,10000] f32 — 256^2 8-wave phase-split GEMM
    gemm_out<<<dim3(T_ * B_ / 256, (V_ + 255) / 256), 512, 0, stream>>>(
        Hcat, 2 * H_, WoutT, 2 * H_, out, V_, b_out, T_ * B_, V_, 2 * H_);
}